// Round 1
// baseline (1277.322 us; speedup 1.0000x reference)
//
#include <hip/hip_runtime.h>
#include <math.h>

#define CIN   128
#define COUT  256
#define HH    64
#define WW    64
#define BB    4
#define KK    9
#define NPIX  4          // output pixels (consecutive wo) per block in main kernel
#define CK    (CIN*KK)   // 1152

// -------------------------------------------------------------------------
// Kernel 1: fused offset(18ch, clipped +-16) + mask(9ch, 2*sigmoid) 3x3 conv
// One thread per output element. Layout: om[((b*27+oc)*64+ho)*64+wo]
// -------------------------------------------------------------------------
__global__ __launch_bounds__(256)
void offmask_conv(const float* __restrict__ x,
                  const float* __restrict__ ow, const float* __restrict__ ob,
                  const float* __restrict__ mw, const float* __restrict__ mb,
                  float* __restrict__ om) {
    int idx = blockIdx.x * 256 + threadIdx.x;
    if (idx >= BB * 27 * HH * WW) return;
    int wo = idx & 63;
    int ho = (idx >> 6) & 63;
    int oc = (idx >> 12) % 27;
    int b  = idx / (27 * HH * WW);

    const float* wbase = (oc < 18) ? (ow + oc * CIN * 9) : (mw + (oc - 18) * CIN * 9);
    const float* xb    = x + b * CIN * HH * WW;

    float acc = 0.f;
    for (int c = 0; c < CIN; ++c) {
        const float* xc = xb + c * HH * WW;
        const float* wc = wbase + c * 9;
#pragma unroll
        for (int ky = 0; ky < 3; ++ky) {
            int y = ho - 1 + ky;
            if (y < 0 || y >= HH) continue;
            const float* row = xc + y * WW;
#pragma unroll
            for (int kx = 0; kx < 3; ++kx) {
                int xx = wo - 1 + kx;
                if (xx < 0 || xx >= WW) continue;
                acc += wc[ky * 3 + kx] * row[xx];
            }
        }
    }
    float v;
    if (oc < 18) {
        v = acc + ob[oc];
        v = fminf(fmaxf(v, -16.f), 16.f);   // max_offset = max(H,W)/4 = 16
    } else {
        v = acc + mb[oc - 18];
        v = 2.f / (1.f + expf(-v));          // 2*sigmoid
    }
    om[idx] = v;
}

// -------------------------------------------------------------------------
// Kernel 2: deformable sampling + per-pixel [256 x 1152] GEMV
// Block = (b, ho, group of NPIX consecutive wo); 256 threads.
// Phase 1: stage sampled*mask values for NPIX pixels into LDS.
// Phase 2: thread t = output channel t; float4 dot against weight row.
// -------------------------------------------------------------------------
__global__ __launch_bounds__(256)
void dcn_main(const float* __restrict__ x, const float* __restrict__ om,
              const float* __restrict__ weight, float* __restrict__ out) {
    int blk = blockIdx.x;            // BB*HH*(WW/NPIX) = 4096
    int wg  = blk & (WW / NPIX - 1); // 16 groups
    int ho  = (blk >> 4) & 63;
    int b   = blk >> 10;
    int wo0 = wg * NPIX;
    int tid = threadIdx.x;

    __shared__ float s_samp[NPIX][CK];       // 18 KB
    __shared__ int   s_idx[NPIX][KK][4];
    __shared__ float s_wgt[NPIX][KK][4];

    // --- bilinear params per (pixel, tap): 36 threads ---
    if (tid < NPIX * KK) {
        int p = tid / KK, k = tid % KK;
        int wo = wo0 + p;
        const float* omb = om + (b * 27) * HH * WW + ho * WW + wo;
        float offy = omb[(2 * k)     * HH * WW];
        float offx = omb[(2 * k + 1) * HH * WW];
        float mval = omb[(18 + k)    * HH * WW];

        float py = (float)(ho - 1 + k / 3) + offy;
        float px = (float)(wo - 1 + k % 3) + offx;
        float y0f = floorf(py), x0f = floorf(px);
        float wy1 = py - y0f,  wx1 = px - x0f;
        float wy0 = 1.f - wy1, wx0 = 1.f - wx1;
        int iy0 = (int)y0f, ix0 = (int)x0f;
        int iy1 = iy0 + 1,  ix1 = ix0 + 1;
        bool vy0 = (iy0 >= 0) && (iy0 < HH);
        bool vy1 = (iy1 >= 0) && (iy1 < HH);
        bool vx0 = (ix0 >= 0) && (ix0 < WW);
        bool vx1 = (ix1 >= 0) && (ix1 < WW);
        int cy0 = min(max(iy0, 0), HH - 1), cy1 = min(max(iy1, 0), HH - 1);
        int cx0 = min(max(ix0, 0), WW - 1), cx1 = min(max(ix1, 0), WW - 1);
        s_idx[p][k][0] = cy0 * WW + cx0;
        s_idx[p][k][1] = cy0 * WW + cx1;
        s_idx[p][k][2] = cy1 * WW + cx0;
        s_idx[p][k][3] = cy1 * WW + cx1;
        s_wgt[p][k][0] = (vy0 && vx0) ? mval * wy0 * wx0 : 0.f;
        s_wgt[p][k][1] = (vy0 && vx1) ? mval * wy0 * wx1 : 0.f;
        s_wgt[p][k][2] = (vy1 && vx0) ? mval * wy1 * wx0 : 0.f;
        s_wgt[p][k][3] = (vy1 && vx1) ? mval * wy1 * wx1 : 0.f;
    }
    __syncthreads();

    // --- phase 1: gather+blend into LDS: NPIX*CK = 4608 entries ---
    const float* xb = x + b * CIN * HH * WW;
    for (int i = tid; i < NPIX * CK; i += 256) {
        int p = i / CK;
        int r = i - p * CK;
        int c = r / KK;
        int k = r - c * KK;
        const float* xc = xb + c * HH * WW;
        float v = s_wgt[p][k][0] * xc[s_idx[p][k][0]]
                + s_wgt[p][k][1] * xc[s_idx[p][k][1]]
                + s_wgt[p][k][2] * xc[s_idx[p][k][2]]
                + s_wgt[p][k][3] * xc[s_idx[p][k][3]];
        s_samp[p][r] = v;
    }
    __syncthreads();

    // --- phase 2: GEMV, thread = output channel ---
    int co = tid;
    const float4* wrow = (const float4*)(weight + co * CK);
    const float4* sp0 = (const float4*)s_samp[0];
    const float4* sp1 = (const float4*)s_samp[1];
    const float4* sp2 = (const float4*)s_samp[2];
    const float4* sp3 = (const float4*)s_samp[3];
    float a0 = 0.f, a1 = 0.f, a2 = 0.f, a3 = 0.f;
#pragma unroll 4
    for (int j = 0; j < CK / 4; ++j) {
        float4 wv = wrow[j];
        float4 v0 = sp0[j], v1 = sp1[j], v2 = sp2[j], v3 = sp3[j];
        a0 += wv.x * v0.x + wv.y * v0.y + wv.z * v0.z + wv.w * v0.w;
        a1 += wv.x * v1.x + wv.y * v1.y + wv.z * v1.z + wv.w * v1.w;
        a2 += wv.x * v2.x + wv.y * v2.y + wv.z * v2.z + wv.w * v2.w;
        a3 += wv.x * v3.x + wv.y * v3.y + wv.z * v3.z + wv.w * v3.w;
    }
    float* op = out + ((b * COUT + co) * HH + ho) * WW + wo0;
    *(float4*)op = make_float4(a0, a1, a2, a3);
}

// -------------------------------------------------------------------------
extern "C" void kernel_launch(void* const* d_in, const int* in_sizes, int n_in,
                              void* d_out, int out_size, void* d_ws, size_t ws_size,
                              hipStream_t stream) {
    const float* x  = (const float*)d_in[0];
    const float* ow = (const float*)d_in[1];
    const float* ob = (const float*)d_in[2];
    const float* mw = (const float*)d_in[3];
    const float* mb = (const float*)d_in[4];
    const float* wt = (const float*)d_in[5];
    float* om  = (float*)d_ws;               // 4*27*64*64 floats = 1.77 MB
    float* out = (float*)d_out;

    int n1 = BB * 27 * HH * WW;              // 442368
    offmask_conv<<<(n1 + 255) / 256, 256, 0, stream>>>(x, ow, ob, mw, mb, om);

    int n2 = BB * HH * (WW / NPIX);          // 4096 blocks
    dcn_main<<<n2, 256, 0, stream>>>(x, om, wt, out);
}

// Round 3
// 422.890 us; speedup vs baseline: 3.0205x; 3.0205x over previous
//
#include <hip/hip_runtime.h>
#include <math.h>

#define CIN   128
#define COUT  256
#define HH    64
#define WW    64
#define BB    4
#define KK    9
#define CK    (CIN*KK)   // 1152

typedef unsigned short u16;
typedef unsigned int   u32;
using f32x4  = __attribute__((ext_vector_type(4))) float;
using s16x8  = __attribute__((ext_vector_type(8))) short;

__device__ __forceinline__ u16 f2bf(float f) {
    union { float f; u32 u; } v; v.f = f;
    u32 u = v.u;
    u += 0x7FFFu + ((u >> 16) & 1u);   // round-to-nearest-even
    return (u16)(u >> 16);
}

// -------------------------------------------------------------------------
// Kernel 0: weight fp32 [co][c][tap] -> bf16, tap-major K: wbf[co][tap*128+c]
// -------------------------------------------------------------------------
__global__ __launch_bounds__(256)
void wprep(const float* __restrict__ w, u16* __restrict__ wbf) {
    int i = blockIdx.x * 256 + threadIdx.x;
    if (i >= COUT * CK) return;
    int co = i / CK;
    int r  = i - co * CK;
    int tap = r >> 7;        // 0..8
    int c   = r & 127;
    wbf[i] = f2bf(w[co * CK + c * 9 + tap]);
}

// -------------------------------------------------------------------------
// Kernel 1: fused offset(18ch, clipped +-16) + mask(9ch, 2*sigmoid) 3x3 conv
// -------------------------------------------------------------------------
__global__ __launch_bounds__(256)
void offmask_conv(const float* __restrict__ x,
                  const float* __restrict__ ow, const float* __restrict__ ob,
                  const float* __restrict__ mw, const float* __restrict__ mb,
                  float* __restrict__ om) {
    int idx = blockIdx.x * 256 + threadIdx.x;
    if (idx >= BB * 27 * HH * WW) return;
    int wo = idx & 63;
    int ho = (idx >> 6) & 63;
    int oc = (idx >> 12) % 27;
    int b  = idx / (27 * HH * WW);

    const float* wbase = (oc < 18) ? (ow + oc * CIN * 9) : (mw + (oc - 18) * CIN * 9);
    const float* xb    = x + b * CIN * HH * WW;

    float acc = 0.f;
    for (int c = 0; c < CIN; ++c) {
        const float* xc = xb + c * HH * WW;
        const float* wc = wbase + c * 9;
#pragma unroll
        for (int ky = 0; ky < 3; ++ky) {
            int y = ho - 1 + ky;
            if (y < 0 || y >= HH) continue;
            const float* row = xc + y * WW;
#pragma unroll
            for (int kx = 0; kx < 3; ++kx) {
                int xx = wo - 1 + kx;
                if (xx < 0 || xx >= WW) continue;
                acc += wc[ky * 3 + kx] * row[xx];
            }
        }
    }
    float v;
    if (oc < 18) {
        v = acc + ob[oc];
        v = fminf(fmaxf(v, -16.f), 16.f);
    } else {
        v = acc + mb[oc - 18];
        v = 2.f / (1.f + expf(-v));
    }
    om[idx] = v;
}

// -------------------------------------------------------------------------
// Kernel 2: deformable sampling + bf16 MFMA GEMM
// Block tile: 32 px (consecutive wo of one (b,ho) row) x 256 co, K=1152.
// K-chunks of 64 are tap-major: chunk=(tap, c-half) so bilinear corner
// idx/weights are shared across the 64 channels of a chunk.
// 4 waves: wv&1 -> px half (16), wv>>1 -> co half (128 = 8 mfma tiles).
// -------------------------------------------------------------------------
__global__ __launch_bounds__(256)
void dcn_mfma(const float* __restrict__ x, const float* __restrict__ om,
              const u16* __restrict__ wbf, float* __restrict__ out) {
    int blk  = blockIdx.x;          // 512 = BB*HH*2
    int half = blk & 1;
    int ho   = (blk >> 1) & 63;
    int b    = blk >> 7;
    int wo0  = half * 32;
    int tid  = threadIdx.x;

    __shared__ u16   Wt[256][72];      // 36.0 KB, row pad 64->72 (16B-aligned rows)
    __shared__ u16   Sm[32][72];       // 4.5 KB
    __shared__ int   s_idx[32][KK][4]; // 4.5 KB
    __shared__ float s_wgt[32][KK][4]; // 4.5 KB

    // --- pre-phase: bilinear corners for 32 px x 9 taps ---
    for (int e = tid; e < 32 * KK; e += 256) {
        int p = e / KK, k = e - (e / KK) * KK;
        int wo = wo0 + p;
        const float* omb = om + (b * 27) * HH * WW + ho * WW + wo;
        float offy = omb[(2 * k)     * HH * WW];
        float offx = omb[(2 * k + 1) * HH * WW];
        float mval = omb[(18 + k)    * HH * WW];

        float py = (float)(ho - 1 + k / 3) + offy;
        float px = (float)(wo - 1 + k % 3) + offx;
        float y0f = floorf(py), x0f = floorf(px);
        float wy1 = py - y0f,  wx1 = px - x0f;
        float wy0 = 1.f - wy1, wx0 = 1.f - wx1;
        int iy0 = (int)y0f, ix0 = (int)x0f;
        int iy1 = iy0 + 1,  ix1 = ix0 + 1;
        bool vy0 = (iy0 >= 0) && (iy0 < HH);
        bool vy1 = (iy1 >= 0) && (iy1 < HH);
        bool vx0 = (ix0 >= 0) && (ix0 < WW);
        bool vx1 = (ix1 >= 0) && (ix1 < WW);
        int cy0 = min(max(iy0, 0), HH - 1), cy1 = min(max(iy1, 0), HH - 1);
        int cx0 = min(max(ix0, 0), WW - 1), cx1 = min(max(ix1, 0), WW - 1);
        s_idx[p][k][0] = cy0 * WW + cx0;
        s_idx[p][k][1] = cy0 * WW + cx1;
        s_idx[p][k][2] = cy1 * WW + cx0;
        s_idx[p][k][3] = cy1 * WW + cx1;
        s_wgt[p][k][0] = (vy0 && vx0) ? mval * wy0 * wx0 : 0.f;
        s_wgt[p][k][1] = (vy0 && vx1) ? mval * wy0 * wx1 : 0.f;
        s_wgt[p][k][2] = (vy1 && vx0) ? mval * wy1 * wx0 : 0.f;
        s_wgt[p][k][3] = (vy1 && vx1) ? mval * wy1 * wx1 : 0.f;
    }

    const float* xb = x + b * CIN * HH * WW;

    int wv   = tid >> 6, lane = tid & 63;
    int quad = lane >> 4, l16 = lane & 15;
    int px_half = wv & 1, co_half = wv >> 1;

    int w_kq  = tid & 7;        // k-quad 0..7 (8 bf16 = 16B each)
    int w_cor = tid >> 3;       // co row 0..31

    int s_px = tid & 31;        // sampling: lane sweeps px (spatially coherent)
    int s_cg = tid >> 5;        // c-group 0..7

    f32x4 acc[8];
#pragma unroll
    for (int i = 0; i < 8; ++i) acc[i] = (f32x4)(0.f);

    for (int chunk = 0; chunk < 18; ++chunk) {
        int tap = chunk >> 1, cb = chunk & 1;
        __syncthreads();   // orders pre-phase (iter 0) / prior MFMA reads (iter>0)

        // --- stage W chunk [256 co][64 k] into LDS (coalesced 16B loads) ---
        const u16* wsrc = wbf + tap * 128 + cb * 64 + w_kq * 8;
#pragma unroll
        for (int r = 0; r < 8; ++r) {
            int co = w_cor + 32 * r;
            *(uint4*)(&Wt[co][w_kq * 8]) = *(const uint4*)(wsrc + co * CK);
        }

        // --- sample S chunk [32 px][64 c] -> LDS bf16 ---
        int   i0 = s_idx[s_px][tap][0], i1 = s_idx[s_px][tap][1];
        int   i2 = s_idx[s_px][tap][2], i3 = s_idx[s_px][tap][3];
        float g0 = s_wgt[s_px][tap][0], g1 = s_wgt[s_px][tap][1];
        float g2 = s_wgt[s_px][tap][2], g3 = s_wgt[s_px][tap][3];
        const float* xcb = xb + cb * 64 * HH * WW;
#pragma unroll
        for (int j = 0; j < 4; ++j) {
            int c = s_cg * 2 + j * 16;
            const float* xc0 = xcb + c * HH * WW;
            const float* xc1 = xc0 + HH * WW;
            float v0 = g0 * xc0[i0] + g1 * xc0[i1] + g2 * xc0[i2] + g3 * xc0[i3];
            float v1 = g0 * xc1[i0] + g1 * xc1[i1] + g2 * xc1[i2] + g3 * xc1[i3];
            *(u32*)(&Sm[s_px][c]) = (u32)f2bf(v0) | ((u32)f2bf(v1) << 16);
        }
        __syncthreads();

        // --- MFMA: 2 k-steps x 8 co-tiles ---
#pragma unroll
        for (int ks = 0; ks < 2; ++ks) {
            s16x8 bfrag = *(const s16x8*)(&Sm[px_half * 16 + l16][ks * 32 + quad * 8]);
#pragma unroll
            for (int ct = 0; ct < 8; ++ct) {
                int co = co_half * 128 + ct * 16 + l16;
                s16x8 afrag = *(const s16x8*)(&Wt[co][ks * 32 + quad * 8]);
                acc[ct] = __builtin_amdgcn_mfma_f32_16x16x32_bf16(afrag, bfrag, acc[ct], 0, 0, 0);
            }
        }
    }

    // --- epilogue: D col = lane&15 -> px = px_half*16 + (lane&15);
    //     row = quad*4+reg -> co. (Round-2 bug: px_half*16 was dropped.)
#pragma unroll
    for (int ct = 0; ct < 8; ++ct) {
        int cobase = co_half * 128 + ct * 16 + quad * 4;
#pragma unroll
        for (int r = 0; r < 4; ++r) {
            int co = cobase + r;
            out[((b * COUT + co) * HH + ho) * WW + wo0 + px_half * 16 + l16] = acc[ct][r];
        }
    }
}

// -------------------------------------------------------------------------
extern "C" void kernel_launch(void* const* d_in, const int* in_sizes, int n_in,
                              void* d_out, int out_size, void* d_ws, size_t ws_size,
                              hipStream_t stream) {
    const float* x  = (const float*)d_in[0];
    const float* ow = (const float*)d_in[1];
    const float* ob = (const float*)d_in[2];
    const float* mw = (const float*)d_in[3];
    const float* mb = (const float*)d_in[4];
    const float* wt = (const float*)d_in[5];

    u16*   wbf = (u16*)d_ws;                                   // 576 KB
    float* om  = (float*)((char*)d_ws + (size_t)COUT * CK * 2); // 1.77 MB
    float* out = (float*)d_out;

    int n0 = COUT * CK;                      // 294912
    wprep<<<(n0 + 255) / 256, 256, 0, stream>>>(wt, wbf);

    int n1 = BB * 27 * HH * WW;              // 442368
    offmask_conv<<<(n1 + 255) / 256, 256, 0, stream>>>(x, ow, ob, mw, mb, om);

    int n2 = BB * HH * 2;                    // 512 blocks (32 px each)
    dcn_mfma<<<n2, 256, 0, stream>>>(x, om, wbf, out);
}

// Round 4
// 273.832 us; speedup vs baseline: 4.6646x; 1.5443x over previous
//
#include <hip/hip_runtime.h>
#include <math.h>

#define CIN   128
#define COUT  256
#define HH    64
#define WW    64
#define BB    4
#define KK    9
#define CK    (CIN*KK)   // 1152

typedef unsigned short u16;
typedef unsigned int   u32;
using f32x4  = __attribute__((ext_vector_type(4))) float;
using s16x8  = __attribute__((ext_vector_type(8))) short;

__device__ __forceinline__ u16 f2bf(float f) {
    union { float f; u32 u; } v; v.f = f;
    u32 u = v.u;
    u += 0x7FFFu + ((u >> 16) & 1u);   // round-to-nearest-even
    return (u16)(u >> 16);
}

// -------------------------------------------------------------------------
// Kernel 0a: main weight fp32 [co][c][tap] -> bf16 tap-major: wbf[co][tap*128+c]
// -------------------------------------------------------------------------
__global__ __launch_bounds__(256)
void wprep(const float* __restrict__ w, u16* __restrict__ wbf) {
    int i = blockIdx.x * 256 + threadIdx.x;
    if (i >= COUT * CK) return;
    int co = i / CK;
    int r  = i - co * CK;
    int tap = r >> 7;
    int c   = r & 127;
    wbf[i] = f2bf(w[co * CK + c * 9 + tap]);
}

// -------------------------------------------------------------------------
// Kernel 0b: offset+mask weights -> wofs[32][1152] bf16 tap-major.
// rows 0..17 = offset conv, 18..26 = mask conv, 27..31 = zero pad.
// -------------------------------------------------------------------------
__global__ __launch_bounds__(256)
void wofs_prep(const float* __restrict__ ow, const float* __restrict__ mw,
               u16* __restrict__ wofs) {
    int i = blockIdx.x * 256 + threadIdx.x;
    if (i >= 32 * CK) return;
    int oc = i / CK;
    int r  = i - oc * CK;
    int tap = r >> 7;
    int c   = r & 127;
    float v = 0.f;
    if (oc < 18)      v = ow[oc * CK + c * 9 + tap];
    else if (oc < 27) v = mw[(oc - 18) * CK + c * 9 + tap];
    wofs[i] = f2bf(v);
}

// -------------------------------------------------------------------------
// Kernel 1: offset+mask conv as bf16 MFMA GEMM. M=32 (27 used), K=1152
// tap-major, block = 32 px (half row of one (b,ho)) -> 512 blocks.
// B-operand is a plain shifted-row copy of x (no gathers).
// Waves: wv&1 -> px half (16), wv>>1 -> co tile (16).
// -------------------------------------------------------------------------
__global__ __launch_bounds__(256)
void offmask_mfma(const float* __restrict__ x, const u16* __restrict__ wofs,
                  const float* __restrict__ ob, const float* __restrict__ mb,
                  float* __restrict__ om) {
    int blk  = blockIdx.x;          // 512 = BB*HH*2
    int half = blk & 1;
    int ho   = (blk >> 1) & 63;
    int b    = blk >> 7;
    int wo0  = half * 32;
    int tid  = threadIdx.x;

    __shared__ u16 Wt[32][72];      // 4.5 KB
    __shared__ u16 Sm[32][72];      // 4.5 KB  (px-major rows, 144B = 9*16B)

    int wv   = tid >> 6, lane = tid & 63;
    int quad = lane >> 4, l16 = lane & 15;
    int px_half = wv & 1, ct = wv >> 1;

    int w_kq  = tid & 7;            // W staging: k-oct (16B)
    int w_cor = tid >> 3;           // co 0..31

    int s_cp = tid & 31;            // S staging: c-pair (c=2cp,2cp+1)
    int s_p0 = tid >> 5;            // px base 0..7 (+8j)

    const float* xb = x + b * CIN * HH * WW;

    f32x4 acc = (f32x4)(0.f);

    for (int chunk = 0; chunk < 18; ++chunk) {
        int tap = chunk >> 1, cb = chunk & 1;
        int ky = tap / 3, kx = tap % 3;
        int y  = ho - 1 + ky;
        bool yok = (y >= 0) && (y < HH);

        __syncthreads();

        // --- stage W chunk [32 co][64 k] ---
        *(uint4*)(&Wt[w_cor][w_kq * 8]) =
            *(const uint4*)(wofs + w_cor * CK + tap * 128 + cb * 64 + w_kq * 8);

        // --- stage S chunk [32 px][64 c]: shifted row copy, zero OOB ---
        const float* xr0 = xb + ((cb * 64 + 2 * s_cp) * HH + (yok ? y : 0)) * WW;
        const float* xr1 = xr0 + HH * WW;
#pragma unroll
        for (int j = 0; j < 4; ++j) {
            int px  = s_p0 + 8 * j;
            int col = wo0 + px + kx - 1;
            bool ok = yok && ((unsigned)col < WW);
            float v0 = ok ? xr0[col] : 0.f;
            float v1 = ok ? xr1[col] : 0.f;
            *(u32*)(&Sm[px][2 * s_cp]) = (u32)f2bf(v0) | ((u32)f2bf(v1) << 16);
        }
        __syncthreads();

        // --- MFMA: 2 k-steps, 1 co-tile per wave ---
#pragma unroll
        for (int ks = 0; ks < 2; ++ks) {
            s16x8 bfrag = *(const s16x8*)(&Sm[px_half * 16 + l16][ks * 32 + quad * 8]);
            s16x8 afrag = *(const s16x8*)(&Wt[ct * 16 + l16][ks * 32 + quad * 8]);
            acc = __builtin_amdgcn_mfma_f32_16x16x32_bf16(afrag, bfrag, acc, 0, 0, 0);
        }
    }

    // --- epilogue: col=lane&15 -> px, row=quad*4+r -> co; bias+nonlinearity ---
    int pxo = wo0 + px_half * 16 + l16;
#pragma unroll
    for (int r = 0; r < 4; ++r) {
        int co = ct * 16 + quad * 4 + r;
        if (co >= 27) break;
        float v = acc[r];
        if (co < 18) {
            v += ob[co];
            v = fminf(fmaxf(v, -16.f), 16.f);      // max_offset = 16
        } else {
            v += mb[co - 18];
            v = 2.f / (1.f + expf(-v));            // 2*sigmoid
        }
        om[((b * 27 + co) * HH + ho) * WW + pxo] = v;
    }
}

// -------------------------------------------------------------------------
// Kernel 2: deformable sampling + bf16 MFMA GEMM (unchanged from round 3)
// -------------------------------------------------------------------------
__global__ __launch_bounds__(256)
void dcn_mfma(const float* __restrict__ x, const float* __restrict__ om,
              const u16* __restrict__ wbf, float* __restrict__ out) {
    int blk  = blockIdx.x;          // 512 = BB*HH*2
    int half = blk & 1;
    int ho   = (blk >> 1) & 63;
    int b    = blk >> 7;
    int wo0  = half * 32;
    int tid  = threadIdx.x;

    __shared__ u16   Wt[256][72];      // 36.0 KB
    __shared__ u16   Sm[32][72];       // 4.5 KB
    __shared__ int   s_idx[32][KK][4]; // 4.5 KB
    __shared__ float s_wgt[32][KK][4]; // 4.5 KB

    for (int e = tid; e < 32 * KK; e += 256) {
        int p = e / KK, k = e - (e / KK) * KK;
        int wo = wo0 + p;
        const float* omb = om + (b * 27) * HH * WW + ho * WW + wo;
        float offy = omb[(2 * k)     * HH * WW];
        float offx = omb[(2 * k + 1) * HH * WW];
        float mval = omb[(18 + k)    * HH * WW];

        float py = (float)(ho - 1 + k / 3) + offy;
        float px = (float)(wo - 1 + k % 3) + offx;
        float y0f = floorf(py), x0f = floorf(px);
        float wy1 = py - y0f,  wx1 = px - x0f;
        float wy0 = 1.f - wy1, wx0 = 1.f - wx1;
        int iy0 = (int)y0f, ix0 = (int)x0f;
        int iy1 = iy0 + 1,  ix1 = ix0 + 1;
        bool vy0 = (iy0 >= 0) && (iy0 < HH);
        bool vy1 = (iy1 >= 0) && (iy1 < HH);
        bool vx0 = (ix0 >= 0) && (ix0 < WW);
        bool vx1 = (ix1 >= 0) && (ix1 < WW);
        int cy0 = min(max(iy0, 0), HH - 1), cy1 = min(max(iy1, 0), HH - 1);
        int cx0 = min(max(ix0, 0), WW - 1), cx1 = min(max(ix1, 0), WW - 1);
        s_idx[p][k][0] = cy0 * WW + cx0;
        s_idx[p][k][1] = cy0 * WW + cx1;
        s_idx[p][k][2] = cy1 * WW + cx0;
        s_idx[p][k][3] = cy1 * WW + cx1;
        s_wgt[p][k][0] = (vy0 && vx0) ? mval * wy0 * wx0 : 0.f;
        s_wgt[p][k][1] = (vy0 && vx1) ? mval * wy0 * wx1 : 0.f;
        s_wgt[p][k][2] = (vy1 && vx0) ? mval * wy1 * wx0 : 0.f;
        s_wgt[p][k][3] = (vy1 && vx1) ? mval * wy1 * wx1 : 0.f;
    }

    const float* xb = x + b * CIN * HH * WW;

    int wv   = tid >> 6, lane = tid & 63;
    int quad = lane >> 4, l16 = lane & 15;
    int px_half = wv & 1, co_half = wv >> 1;

    int w_kq  = tid & 7;
    int w_cor = tid >> 3;

    int s_px = tid & 31;
    int s_cg = tid >> 5;

    f32x4 acc[8];
#pragma unroll
    for (int i = 0; i < 8; ++i) acc[i] = (f32x4)(0.f);

    for (int chunk = 0; chunk < 18; ++chunk) {
        int tap = chunk >> 1, cb = chunk & 1;
        __syncthreads();

        const u16* wsrc = wbf + tap * 128 + cb * 64 + w_kq * 8;
#pragma unroll
        for (int r = 0; r < 8; ++r) {
            int co = w_cor + 32 * r;
            *(uint4*)(&Wt[co][w_kq * 8]) = *(const uint4*)(wsrc + co * CK);
        }

        int   i0 = s_idx[s_px][tap][0], i1 = s_idx[s_px][tap][1];
        int   i2 = s_idx[s_px][tap][2], i3 = s_idx[s_px][tap][3];
        float g0 = s_wgt[s_px][tap][0], g1 = s_wgt[s_px][tap][1];
        float g2 = s_wgt[s_px][tap][2], g3 = s_wgt[s_px][tap][3];
        const float* xcb = xb + cb * 64 * HH * WW;
#pragma unroll
        for (int j = 0; j < 4; ++j) {
            int c = s_cg * 2 + j * 16;
            const float* xc0 = xcb + c * HH * WW;
            const float* xc1 = xc0 + HH * WW;
            float v0 = g0 * xc0[i0] + g1 * xc0[i1] + g2 * xc0[i2] + g3 * xc0[i3];
            float v1 = g0 * xc1[i0] + g1 * xc1[i1] + g2 * xc1[i2] + g3 * xc1[i3];
            *(u32*)(&Sm[s_px][c]) = (u32)f2bf(v0) | ((u32)f2bf(v1) << 16);
        }
        __syncthreads();

#pragma unroll
        for (int ks = 0; ks < 2; ++ks) {
            s16x8 bfrag = *(const s16x8*)(&Sm[px_half * 16 + l16][ks * 32 + quad * 8]);
#pragma unroll
            for (int ct = 0; ct < 8; ++ct) {
                int co = co_half * 128 + ct * 16 + l16;
                s16x8 afrag = *(const s16x8*)(&Wt[co][ks * 32 + quad * 8]);
                acc[ct] = __builtin_amdgcn_mfma_f32_16x16x32_bf16(afrag, bfrag, acc[ct], 0, 0, 0);
            }
        }
    }

#pragma unroll
    for (int ct = 0; ct < 8; ++ct) {
        int cobase = co_half * 128 + ct * 16 + quad * 4;
#pragma unroll
        for (int r = 0; r < 4; ++r) {
            int co = cobase + r;
            out[((b * COUT + co) * HH + ho) * WW + wo0 + px_half * 16 + l16] = acc[ct][r];
        }
    }
}

// -------------------------------------------------------------------------
extern "C" void kernel_launch(void* const* d_in, const int* in_sizes, int n_in,
                              void* d_out, int out_size, void* d_ws, size_t ws_size,
                              hipStream_t stream) {
    const float* x  = (const float*)d_in[0];
    const float* ow = (const float*)d_in[1];
    const float* ob = (const float*)d_in[2];
    const float* mw = (const float*)d_in[3];
    const float* mb = (const float*)d_in[4];
    const float* wt = (const float*)d_in[5];

    char* ws = (char*)d_ws;
    u16*   wbf  = (u16*)ws;                          ws += (size_t)COUT * CK * 2;  // 576 KB
    u16*   wofs = (u16*)ws;                          ws += (size_t)32 * CK * 2;    // 72 KB
    float* om   = (float*)ws;                                                      // 1.77 MB
    float* out  = (float*)d_out;

    int n0 = COUT * CK;
    wprep<<<(n0 + 255) / 256, 256, 0, stream>>>(wt, wbf);

    int n0b = 32 * CK;
    wofs_prep<<<(n0b + 255) / 256, 256, 0, stream>>>(ow, mw, wofs);

    offmask_mfma<<<BB * HH * 2, 256, 0, stream>>>(x, wofs, ob, mb, om);

    dcn_mfma<<<BB * HH * 2, 256, 0, stream>>>(x, om, wbf, out);
}

// Round 5
// 239.359 us; speedup vs baseline: 5.3364x; 1.1440x over previous
//
#include <hip/hip_runtime.h>
#include <math.h>

#define CIN   128
#define COUT  256
#define HH    64
#define WW    64
#define BB    4
#define KK    9
#define CK    (CIN*KK)   // 1152

typedef unsigned short u16;
typedef unsigned int   u32;
using f32x4  = __attribute__((ext_vector_type(4))) float;
using s16x8  = __attribute__((ext_vector_type(8))) short;

__device__ __forceinline__ u16 f2bf(float f) {
    union { float f; u32 u; } v; v.f = f;
    u32 u = v.u;
    u += 0x7FFFu + ((u >> 16) & 1u);   // round-to-nearest-even
    return (u16)(u >> 16);
}

// XCD-aware block swizzle: blockIdx%8 = XCD (dispatch round-robin heuristic).
// Each XCD owns a 32-row half of one batch -> per-XCD L2 working set
// (x band ~1.7MB + W 0.58MB) fits in the 4MB XCD L2. Perf-only heuristic.
__device__ __forceinline__ void blk_map(int blkid, int& b, int& ho, int& wo0) {
    int xcd = blkid & 7, idx = blkid >> 3;
    b   = xcd >> 1;
    ho  = ((xcd & 1) << 5) + (idx >> 1);
    wo0 = (idx & 1) << 5;
}

// -------------------------------------------------------------------------
// Kernel 0a: main weight fp32 [co][c][tap] -> bf16 tap-major: wbf[co][tap*128+c]
// -------------------------------------------------------------------------
__global__ __launch_bounds__(256)
void wprep(const float* __restrict__ w, u16* __restrict__ wbf) {
    int i = blockIdx.x * 256 + threadIdx.x;
    if (i >= COUT * CK) return;
    int co = i / CK;
    int r  = i - co * CK;
    int tap = r >> 7;
    int c   = r & 127;
    wbf[i] = f2bf(w[co * CK + c * 9 + tap]);
}

// -------------------------------------------------------------------------
// Kernel 0b: offset+mask weights -> wofs[32][1152] bf16 tap-major.
// -------------------------------------------------------------------------
__global__ __launch_bounds__(256)
void wofs_prep(const float* __restrict__ ow, const float* __restrict__ mw,
               u16* __restrict__ wofs) {
    int i = blockIdx.x * 256 + threadIdx.x;
    if (i >= 32 * CK) return;
    int oc = i / CK;
    int r  = i - oc * CK;
    int tap = r >> 7;
    int c   = r & 127;
    float v = 0.f;
    if (oc < 18)      v = ow[oc * CK + c * 9 + tap];
    else if (oc < 27) v = mw[(oc - 18) * CK + c * 9 + tap];
    wofs[i] = f2bf(v);
}

// -------------------------------------------------------------------------
// Kernel 1: offset+mask conv as bf16 MFMA GEMM (round-4 version + swizzle)
// -------------------------------------------------------------------------
__global__ __launch_bounds__(256)
void offmask_mfma(const float* __restrict__ x, const u16* __restrict__ wofs,
                  const float* __restrict__ ob, const float* __restrict__ mb,
                  float* __restrict__ om) {
    int b, ho, wo0;
    blk_map(blockIdx.x, b, ho, wo0);
    int tid  = threadIdx.x;

    __shared__ u16 Wt[32][72];
    __shared__ u16 Sm[32][72];

    int wv   = tid >> 6, lane = tid & 63;
    int quad = lane >> 4, l16 = lane & 15;
    int px_half = wv & 1, ct = wv >> 1;

    int w_kq  = tid & 7;
    int w_cor = tid >> 3;

    int s_cp = tid & 31;
    int s_p0 = tid >> 5;

    const float* xb = x + b * CIN * HH * WW;

    f32x4 acc = (f32x4)(0.f);

    for (int chunk = 0; chunk < 18; ++chunk) {
        int tap = chunk >> 1;
        int koff = chunk * 64;            // == tap*128 + (chunk&1)*64
        int cb = chunk & 1;
        int ky = tap / 3, kx = tap % 3;
        int y  = ho - 1 + ky;
        bool yok = (y >= 0) && (y < HH);

        __syncthreads();

        *(uint4*)(&Wt[w_cor][w_kq * 8]) =
            *(const uint4*)(wofs + w_cor * CK + koff + w_kq * 8);

        const float* xr0 = xb + ((cb * 64 + 2 * s_cp) * HH + (yok ? y : 0)) * WW;
        const float* xr1 = xr0 + HH * WW;
#pragma unroll
        for (int j = 0; j < 4; ++j) {
            int px  = s_p0 + 8 * j;
            int col = wo0 + px + kx - 1;
            bool ok = yok && ((unsigned)col < WW);
            float v0 = ok ? xr0[col] : 0.f;
            float v1 = ok ? xr1[col] : 0.f;
            *(u32*)(&Sm[px][2 * s_cp]) = (u32)f2bf(v0) | ((u32)f2bf(v1) << 16);
        }
        __syncthreads();

#pragma unroll
        for (int ks = 0; ks < 2; ++ks) {
            s16x8 bfrag = *(const s16x8*)(&Sm[px_half * 16 + l16][ks * 32 + quad * 8]);
            s16x8 afrag = *(const s16x8*)(&Wt[ct * 16 + l16][ks * 32 + quad * 8]);
            acc = __builtin_amdgcn_mfma_f32_16x16x32_bf16(afrag, bfrag, acc, 0, 0, 0);
        }
    }

    int pxo = wo0 + px_half * 16 + l16;
#pragma unroll
    for (int r = 0; r < 4; ++r) {
        int co = ct * 16 + quad * 4 + r;
        if (co >= 27) break;
        float v = acc[r];
        if (co < 18) {
            v += ob[co];
            v = fminf(fmaxf(v, -16.f), 16.f);
        } else {
            v += mb[co - 18];
            v = 2.f / (1.f + expf(-v));
        }
        om[((b * 27 + co) * HH + ho) * WW + pxo] = v;
    }
}

// -------------------------------------------------------------------------
// Kernel 2: deformable sampling + bf16 MFMA GEMM.
// Round-5 changes: (a) W read direct global->afrag (ws layout is
// fragment-perfect; kills 36KB Wt LDS + its 8-way bank conflicts),
// (b) XCD swizzle. Sm/B-operand path unchanged (verified).
// -------------------------------------------------------------------------
__global__ __launch_bounds__(256)
void dcn_mfma(const float* __restrict__ x, const float* __restrict__ om,
              const u16* __restrict__ wbf, float* __restrict__ out) {
    int b, ho, wo0;
    blk_map(blockIdx.x, b, ho, wo0);
    int tid  = threadIdx.x;

    __shared__ u16   Sm[32][72];       // 4.5 KB
    __shared__ int   s_idx[32][KK][4]; // 4.5 KB
    __shared__ float s_wgt[32][KK][4]; // 4.5 KB

    for (int e = tid; e < 32 * KK; e += 256) {
        int p = e / KK, k = e - (e / KK) * KK;
        int wo = wo0 + p;
        const float* omb = om + (b * 27) * HH * WW + ho * WW + wo;
        float offy = omb[(2 * k)     * HH * WW];
        float offx = omb[(2 * k + 1) * HH * WW];
        float mval = omb[(18 + k)    * HH * WW];

        float py = (float)(ho - 1 + k / 3) + offy;
        float px = (float)(wo - 1 + k % 3) + offx;
        float y0f = floorf(py), x0f = floorf(px);
        float wy1 = py - y0f,  wx1 = px - x0f;
        float wy0 = 1.f - wy1, wx0 = 1.f - wx1;
        int iy0 = (int)y0f, ix0 = (int)x0f;
        int iy1 = iy0 + 1,  ix1 = ix0 + 1;
        bool vy0 = (iy0 >= 0) && (iy0 < HH);
        bool vy1 = (iy1 >= 0) && (iy1 < HH);
        bool vx0 = (ix0 >= 0) && (ix0 < WW);
        bool vx1 = (ix1 >= 0) && (ix1 < WW);
        int cy0 = min(max(iy0, 0), HH - 1), cy1 = min(max(iy1, 0), HH - 1);
        int cx0 = min(max(ix0, 0), WW - 1), cx1 = min(max(ix1, 0), WW - 1);
        s_idx[p][k][0] = cy0 * WW + cx0;
        s_idx[p][k][1] = cy0 * WW + cx1;
        s_idx[p][k][2] = cy1 * WW + cx0;
        s_idx[p][k][3] = cy1 * WW + cx1;
        s_wgt[p][k][0] = (vy0 && vx0) ? mval * wy0 * wx0 : 0.f;
        s_wgt[p][k][1] = (vy0 && vx1) ? mval * wy0 * wx1 : 0.f;
        s_wgt[p][k][2] = (vy1 && vx0) ? mval * wy1 * wx0 : 0.f;
        s_wgt[p][k][3] = (vy1 && vx1) ? mval * wy1 * wx1 : 0.f;
    }

    const float* xb = x + b * CIN * HH * WW;

    int wv   = tid >> 6, lane = tid & 63;
    int quad = lane >> 4, l16 = lane & 15;
    int px_half = wv & 1, co_half = wv >> 1;

    int s_px = tid & 31;
    int s_cg = tid >> 5;

    // per-wave fragment-ready W base: row = co_half*128 + l16 (+ ct*16)
    const u16* wbase = wbf + (co_half * 128 + l16) * CK + quad * 8;

    f32x4 acc[8];
#pragma unroll
    for (int i = 0; i < 8; ++i) acc[i] = (f32x4)(0.f);

    for (int chunk = 0; chunk < 18; ++chunk) {
        int tap  = chunk >> 1;
        int koff = chunk * 64;
        int cb   = chunk & 1;
        __syncthreads();

        int   i0 = s_idx[s_px][tap][0], i1 = s_idx[s_px][tap][1];
        int   i2 = s_idx[s_px][tap][2], i3 = s_idx[s_px][tap][3];
        float g0 = s_wgt[s_px][tap][0], g1 = s_wgt[s_px][tap][1];
        float g2 = s_wgt[s_px][tap][2], g3 = s_wgt[s_px][tap][3];
        const float* xcb = xb + cb * 64 * HH * WW;
#pragma unroll
        for (int j = 0; j < 4; ++j) {
            int c = s_cg * 2 + j * 16;
            const float* xc0 = xcb + c * HH * WW;
            const float* xc1 = xc0 + HH * WW;
            float v0 = g0 * xc0[i0] + g1 * xc0[i1] + g2 * xc0[i2] + g3 * xc0[i3];
            float v1 = g0 * xc1[i0] + g1 * xc1[i1] + g2 * xc1[i2] + g3 * xc1[i3];
            *(u32*)(&Sm[s_px][c]) = (u32)f2bf(v0) | ((u32)f2bf(v1) << 16);
        }
        __syncthreads();

#pragma unroll
        for (int ks = 0; ks < 2; ++ks) {
            s16x8 bfrag = *(const s16x8*)(&Sm[px_half * 16 + l16][ks * 32 + quad * 8]);
#pragma unroll
            for (int ct = 0; ct < 8; ++ct) {
                s16x8 afrag = *(const s16x8*)(wbase + ct * 16 * CK + koff + ks * 32);
                acc[ct] = __builtin_amdgcn_mfma_f32_16x16x32_bf16(afrag, bfrag, acc[ct], 0, 0, 0);
            }
        }
    }

#pragma unroll
    for (int ct = 0; ct < 8; ++ct) {
        int cobase = co_half * 128 + ct * 16 + quad * 4;
#pragma unroll
        for (int r = 0; r < 4; ++r) {
            int co = cobase + r;
            out[((b * COUT + co) * HH + ho) * WW + wo0 + px_half * 16 + l16] = acc[ct][r];
        }
    }
}

// -------------------------------------------------------------------------
extern "C" void kernel_launch(void* const* d_in, const int* in_sizes, int n_in,
                              void* d_out, int out_size, void* d_ws, size_t ws_size,
                              hipStream_t stream) {
    const float* x  = (const float*)d_in[0];
    const float* ow = (const float*)d_in[1];
    const float* ob = (const float*)d_in[2];
    const float* mw = (const float*)d_in[3];
    const float* mb = (const float*)d_in[4];
    const float* wt = (const float*)d_in[5];

    char* ws = (char*)d_ws;
    u16*   wbf  = (u16*)ws;                          ws += (size_t)COUT * CK * 2;  // 576 KB
    u16*   wofs = (u16*)ws;                          ws += (size_t)32 * CK * 2;    // 72 KB
    float* om   = (float*)ws;                                                      // 1.77 MB
    float* out  = (float*)d_out;

    int n0 = COUT * CK;
    wprep<<<(n0 + 255) / 256, 256, 0, stream>>>(wt, wbf);

    int n0b = 32 * CK;
    wofs_prep<<<(n0b + 255) / 256, 256, 0, stream>>>(ow, mw, wofs);

    offmask_mfma<<<BB * HH * 2, 256, 0, stream>>>(x, wofs, ob, mb, om);

    dcn_mfma<<<BB * HH * 2, 256, 0, stream>>>(x, om, wbf, out);
}

// Round 6
// 217.142 us; speedup vs baseline: 5.8824x; 1.1023x over previous
//
#include <hip/hip_runtime.h>
#include <math.h>

#define CIN   128
#define COUT  256
#define HH    64
#define WW    64
#define BB    4
#define KK    9
#define CK    (CIN*KK)   // 1152

typedef unsigned short u16;
typedef unsigned int   u32;
using f32x4  = __attribute__((ext_vector_type(4))) float;
using s16x8  = __attribute__((ext_vector_type(8))) short;

__device__ __forceinline__ u16 f2bf(float f) {
    union { float f; u32 u; } v; v.f = f;
    u32 u = v.u;
    u += 0x7FFFu + ((u >> 16) & 1u);   // round-to-nearest-even
    return (u16)(u >> 16);
}

// XCD-aware swizzle, 512-block variant (offmask): blk&7 = XCD.
__device__ __forceinline__ void blk_map512(int blkid, int& b, int& ho, int& wo0) {
    int xcd = blkid & 7, idx = blkid >> 3;
    b   = xcd >> 1;
    ho  = ((xcd & 1) << 5) + (idx >> 1);
    wo0 = (idx & 1) << 5;
}

// -------------------------------------------------------------------------
// Kernel 0a: main weight fp32 [co][c][tap] -> bf16 tap-major: wbf[co][tap*128+c]
// -------------------------------------------------------------------------
__global__ __launch_bounds__(256)
void wprep(const float* __restrict__ w, u16* __restrict__ wbf) {
    int i = blockIdx.x * 256 + threadIdx.x;
    if (i >= COUT * CK) return;
    int co = i / CK;
    int r  = i - co * CK;
    int tap = r >> 7;
    int c   = r & 127;
    wbf[i] = f2bf(w[co * CK + c * 9 + tap]);
}

// -------------------------------------------------------------------------
// Kernel 0b: offset+mask weights -> wofs[32][1152] bf16 tap-major.
// -------------------------------------------------------------------------
__global__ __launch_bounds__(256)
void wofs_prep(const float* __restrict__ ow, const float* __restrict__ mw,
               u16* __restrict__ wofs) {
    int i = blockIdx.x * 256 + threadIdx.x;
    if (i >= 32 * CK) return;
    int oc = i / CK;
    int r  = i - oc * CK;
    int tap = r >> 7;
    int c   = r & 127;
    float v = 0.f;
    if (oc < 18)      v = ow[oc * CK + c * 9 + tap];
    else if (oc < 27) v = mw[(oc - 18) * CK + c * 9 + tap];
    wofs[i] = f2bf(v);
}

// -------------------------------------------------------------------------
// Kernel 1: offset+mask conv as bf16 MFMA GEMM (unchanged from round 5)
// -------------------------------------------------------------------------
__global__ __launch_bounds__(256)
void offmask_mfma(const float* __restrict__ x, const u16* __restrict__ wofs,
                  const float* __restrict__ ob, const float* __restrict__ mb,
                  float* __restrict__ om) {
    int b, ho, wo0;
    blk_map512(blockIdx.x, b, ho, wo0);
    int tid  = threadIdx.x;

    __shared__ u16 Wt[32][72];
    __shared__ u16 Sm[32][72];

    int wv   = tid >> 6, lane = tid & 63;
    int quad = lane >> 4, l16 = lane & 15;
    int px_half = wv & 1, ct = wv >> 1;

    int w_kq  = tid & 7;
    int w_cor = tid >> 3;

    int s_cp = tid & 31;
    int s_p0 = tid >> 5;

    const float* xb = x + b * CIN * HH * WW;

    f32x4 acc = (f32x4)(0.f);

    for (int chunk = 0; chunk < 18; ++chunk) {
        int tap = chunk >> 1;
        int koff = chunk * 64;
        int cb = chunk & 1;
        int ky = tap / 3, kx = tap % 3;
        int y  = ho - 1 + ky;
        bool yok = (y >= 0) && (y < HH);

        __syncthreads();

        *(uint4*)(&Wt[w_cor][w_kq * 8]) =
            *(const uint4*)(wofs + w_cor * CK + koff + w_kq * 8);

        const float* xr0 = xb + ((cb * 64 + 2 * s_cp) * HH + (yok ? y : 0)) * WW;
        const float* xr1 = xr0 + HH * WW;
#pragma unroll
        for (int j = 0; j < 4; ++j) {
            int px  = s_p0 + 8 * j;
            int col = wo0 + px + kx - 1;
            bool ok = yok && ((unsigned)col < WW);
            float v0 = ok ? xr0[col] : 0.f;
            float v1 = ok ? xr1[col] : 0.f;
            *(u32*)(&Sm[px][2 * s_cp]) = (u32)f2bf(v0) | ((u32)f2bf(v1) << 16);
        }
        __syncthreads();

#pragma unroll
        for (int ks = 0; ks < 2; ++ks) {
            s16x8 bfrag = *(const s16x8*)(&Sm[px_half * 16 + l16][ks * 32 + quad * 8]);
            s16x8 afrag = *(const s16x8*)(&Wt[ct * 16 + l16][ks * 32 + quad * 8]);
            acc = __builtin_amdgcn_mfma_f32_16x16x32_bf16(afrag, bfrag, acc, 0, 0, 0);
        }
    }

    int pxo = wo0 + px_half * 16 + l16;
#pragma unroll
    for (int r = 0; r < 4; ++r) {
        int co = ct * 16 + quad * 4 + r;
        if (co >= 27) break;
        float v = acc[r];
        if (co < 18) {
            v += ob[co];
            v = fminf(fmaxf(v, -16.f), 16.f);
        } else {
            v += mb[co - 18];
            v = 2.f / (1.f + expf(-v));
        }
        om[((b * 27 + co) * HH + ho) * WW + pxo] = v;
    }
}

// -------------------------------------------------------------------------
// Kernel 2: deformable sampling + bf16 MFMA GEMM.
// Round-6: 16-px blocks (1024 blocks -> 4 blocks/CU, 16 waves/CU) +
// software-pipelined gathers with double-buffered Sm, ONE barrier/iter.
// Each wave owns a co-quarter (64 co = 4 mfma tiles); all waves share px.
// -------------------------------------------------------------------------
__global__ __launch_bounds__(256)
void dcn_mfma(const float* __restrict__ x, const float* __restrict__ om,
              const u16* __restrict__ wbf, float* __restrict__ out) {
    int blkid = blockIdx.x;          // 1024 = BB*HH*4
    int xcd = blkid & 7, idx = blkid >> 3;
    int b   = xcd >> 1;
    int ho  = ((xcd & 1) << 5) + (idx >> 2);
    int wo0 = (idx & 3) << 4;
    int tid = threadIdx.x;

    __shared__ u16   Sm[2][16][72];    // 4.5 KB double-buffered
    __shared__ int   s_idx[16][KK][4]; // 2.25 KB
    __shared__ float s_wgt[16][KK][4]; // 2.25 KB

    // --- pre-phase: bilinear corners for 16 px x 9 taps = 144 entries ---
    if (tid < 16 * KK) {
        int p = tid / KK, k = tid - (tid / KK) * KK;
        int wo = wo0 + p;
        const float* omb = om + (b * 27) * HH * WW + ho * WW + wo;
        float offy = omb[(2 * k)     * HH * WW];
        float offx = omb[(2 * k + 1) * HH * WW];
        float mval = omb[(18 + k)    * HH * WW];

        float py = (float)(ho - 1 + k / 3) + offy;
        float px = (float)(wo - 1 + k % 3) + offx;
        float y0f = floorf(py), x0f = floorf(px);
        float wy1 = py - y0f,  wx1 = px - x0f;
        float wy0 = 1.f - wy1, wx0 = 1.f - wx1;
        int iy0 = (int)y0f, ix0 = (int)x0f;
        int iy1 = iy0 + 1,  ix1 = ix0 + 1;
        bool vy0 = (iy0 >= 0) && (iy0 < HH);
        bool vy1 = (iy1 >= 0) && (iy1 < HH);
        bool vx0 = (ix0 >= 0) && (ix0 < WW);
        bool vx1 = (ix1 >= 0) && (ix1 < WW);
        int cy0 = min(max(iy0, 0), HH - 1), cy1 = min(max(iy1, 0), HH - 1);
        int cx0 = min(max(ix0, 0), WW - 1), cx1 = min(max(ix1, 0), WW - 1);
        s_idx[p][k][0] = cy0 * WW + cx0;
        s_idx[p][k][1] = cy0 * WW + cx1;
        s_idx[p][k][2] = cy1 * WW + cx0;
        s_idx[p][k][3] = cy1 * WW + cx1;
        s_wgt[p][k][0] = (vy0 && vx0) ? mval * wy0 * wx0 : 0.f;
        s_wgt[p][k][1] = (vy0 && vx1) ? mval * wy0 * wx1 : 0.f;
        s_wgt[p][k][2] = (vy1 && vx0) ? mval * wy1 * wx0 : 0.f;
        s_wgt[p][k][3] = (vy1 && vx1) ? mval * wy1 * wx1 : 0.f;
    }
    __syncthreads();

    const float* xb = x + b * CIN * HH * WW;

    int wv   = tid >> 6, lane = tid & 63;
    int quad = lane >> 4, l16 = lane & 15;

    int s_px = tid & 15;     // sampling: lane sweeps px
    int s_cg = tid >> 4;     // c-pair group 0..15 (c = 2*s_cg + 32j, j=0,1)

    // fragment-ready W base: row co = wv*64 + ct*16 + l16, 16B at quad*8 u16
    const u16* wbase = wbf + (wv * 64 + l16) * CK + quad * 8;

    f32x4 acc[4];
#pragma unroll
    for (int i = 0; i < 4; ++i) acc[i] = (f32x4)(0.f);

    auto gather = [&](int chunk, float v[4]) {
        int tap = chunk >> 1, cb = chunk & 1;
        int   i0 = s_idx[s_px][tap][0], i1 = s_idx[s_px][tap][1];
        int   i2 = s_idx[s_px][tap][2], i3 = s_idx[s_px][tap][3];
        float g0 = s_wgt[s_px][tap][0], g1 = s_wgt[s_px][tap][1];
        float g2 = s_wgt[s_px][tap][2], g3 = s_wgt[s_px][tap][3];
        const float* xcb = xb + cb * 64 * HH * WW;
#pragma unroll
        for (int j = 0; j < 2; ++j) {
            int c = 2 * s_cg + 32 * j;
            const float* xc0 = xcb + c * HH * WW;
            const float* xc1 = xc0 + HH * WW;
            v[2*j]   = g0 * xc0[i0] + g1 * xc0[i1] + g2 * xc0[i2] + g3 * xc0[i3];
            v[2*j+1] = g0 * xc1[i0] + g1 * xc1[i1] + g2 * xc1[i2] + g3 * xc1[i3];
        }
    };

    float vc[4], vn[4];
    gather(0, vc);
    int buf = 0;

    for (int chunk = 0; chunk < 18; ++chunk) {
        // write current chunk's samples to Sm[buf] (bf16-packed)
        *(u32*)(&Sm[buf][s_px][2 * s_cg])      = (u32)f2bf(vc[0]) | ((u32)f2bf(vc[1]) << 16);
        *(u32*)(&Sm[buf][s_px][2 * s_cg + 32]) = (u32)f2bf(vc[2]) | ((u32)f2bf(vc[3]) << 16);
        __syncthreads();   // one barrier/iter; dbuf makes write(k+2)/read(k) safe

        if (chunk < 17) gather(chunk + 1, vn);   // latency overlaps MFMAs below

        int koff = chunk * 64;
#pragma unroll
        for (int ks = 0; ks < 2; ++ks) {
            s16x8 bfrag = *(const s16x8*)(&Sm[buf][l16][ks * 32 + quad * 8]);
#pragma unroll
            for (int ct = 0; ct < 4; ++ct) {
                s16x8 afrag = *(const s16x8*)(wbase + ct * 16 * CK + koff + ks * 32);
                acc[ct] = __builtin_amdgcn_mfma_f32_16x16x32_bf16(afrag, bfrag, acc[ct], 0, 0, 0);
            }
        }
#pragma unroll
        for (int q = 0; q < 4; ++q) vc[q] = vn[q];
        buf ^= 1;
    }

    // epilogue: col = l16 -> wo0+l16; row = quad*4+r -> co within wave quarter
#pragma unroll
    for (int ct = 0; ct < 4; ++ct) {
        int cobase = wv * 64 + ct * 16 + quad * 4;
#pragma unroll
        for (int r = 0; r < 4; ++r) {
            int co = cobase + r;
            out[((b * COUT + co) * HH + ho) * WW + wo0 + l16] = acc[ct][r];
        }
    }
}

// -------------------------------------------------------------------------
extern "C" void kernel_launch(void* const* d_in, const int* in_sizes, int n_in,
                              void* d_out, int out_size, void* d_ws, size_t ws_size,
                              hipStream_t stream) {
    const float* x  = (const float*)d_in[0];
    const float* ow = (const float*)d_in[1];
    const float* ob = (const float*)d_in[2];
    const float* mw = (const float*)d_in[3];
    const float* mb = (const float*)d_in[4];
    const float* wt = (const float*)d_in[5];

    char* ws = (char*)d_ws;
    u16*   wbf  = (u16*)ws;                          ws += (size_t)COUT * CK * 2;  // 576 KB
    u16*   wofs = (u16*)ws;                          ws += (size_t)32 * CK * 2;    // 72 KB
    float* om   = (float*)ws;                                                      // 1.77 MB
    float* out  = (float*)d_out;

    int n0 = COUT * CK;
    wprep<<<(n0 + 255) / 256, 256, 0, stream>>>(wt, wbf);

    int n0b = 32 * CK;
    wofs_prep<<<(n0b + 255) / 256, 256, 0, stream>>>(ow, mw, wofs);

    offmask_mfma<<<BB * HH * 2, 256, 0, stream>>>(x, wofs, ob, mb, om);

    dcn_mfma<<<BB * HH * 4, 256, 0, stream>>>(x, om, wbf, out);
}

// Round 7
// 184.946 us; speedup vs baseline: 6.9065x; 1.1741x over previous
//
#include <hip/hip_runtime.h>
#include <math.h>

#define CIN   128
#define COUT  256
#define HH    64
#define WW    64
#define BB    4
#define KK    9
#define CK    (CIN*KK)   // 1152

typedef unsigned short u16;
typedef unsigned int   u32;
using f32x4  = __attribute__((ext_vector_type(4))) float;
using s16x8  = __attribute__((ext_vector_type(8))) short;

__device__ __forceinline__ u16 f2bf(float f) {
    union { float f; u32 u; } v; v.f = f;
    u32 u = v.u;
    u += 0x7FFFu + ((u >> 16) & 1u);   // round-to-nearest-even
    return (u16)(u >> 16);
}

// XCD-aware swizzle, 512-block variant (offmask): blk&7 = XCD.
__device__ __forceinline__ void blk_map512(int blkid, int& b, int& ho, int& wo0) {
    int xcd = blkid & 7, idx = blkid >> 3;
    b   = xcd >> 1;
    ho  = ((xcd & 1) << 5) + (idx >> 1);
    wo0 = (idx & 1) << 5;
}

// -------------------------------------------------------------------------
// Kernel 0a: main weight -> MFMA-fragment-ordered bf16.
// wfrag u16 index = (((chunk*4 + wv)*4 + ct)*2 + ks)*512 + lane*8 + j
// holds W[co = wv*64+ct*16+(lane&15)][k = chunk*64+ks*32+(lane>>4)*8+j]
// (k tap-major: tap=k>>7, c=k&127). afrag load in dcn_mfma is then
// wave-uniform-base + lane*16B -> one coalesced 1KB load per fragment.
// -------------------------------------------------------------------------
__global__ __launch_bounds__(256)
void wprep(const float* __restrict__ w, u16* __restrict__ wfrag) {
    int i = blockIdx.x * 256 + threadIdx.x;    // destination u16 index
    if (i >= COUT * CK) return;
    int j     = i & 7;
    int lane  = (i >> 3) & 63;
    int ks    = (i >> 9) & 1;
    int ct    = (i >> 10) & 3;
    int wv    = (i >> 12) & 3;
    int chunk = i >> 14;                       // 0..17
    int co  = wv * 64 + ct * 16 + (lane & 15);
    int k   = chunk * 64 + ks * 32 + (lane >> 4) * 8 + j;
    int tap = k >> 7, c = k & 127;
    wfrag[i] = f2bf(w[co * CK + c * 9 + tap]);
}

// -------------------------------------------------------------------------
// Kernel 0b: offset+mask weights -> wofs[32][1152] bf16 tap-major.
// -------------------------------------------------------------------------
__global__ __launch_bounds__(256)
void wofs_prep(const float* __restrict__ ow, const float* __restrict__ mw,
               u16* __restrict__ wofs) {
    int i = blockIdx.x * 256 + threadIdx.x;
    if (i >= 32 * CK) return;
    int oc = i / CK;
    int r  = i - oc * CK;
    int tap = r >> 7;
    int c   = r & 127;
    float v = 0.f;
    if (oc < 18)      v = ow[oc * CK + c * 9 + tap];
    else if (oc < 27) v = mw[(oc - 18) * CK + c * 9 + tap];
    wofs[i] = f2bf(v);
}

// -------------------------------------------------------------------------
// Kernel 1: offset+mask conv as bf16 MFMA GEMM (unchanged)
// -------------------------------------------------------------------------
__global__ __launch_bounds__(256)
void offmask_mfma(const float* __restrict__ x, const u16* __restrict__ wofs,
                  const float* __restrict__ ob, const float* __restrict__ mb,
                  float* __restrict__ om) {
    int b, ho, wo0;
    blk_map512(blockIdx.x, b, ho, wo0);
    int tid  = threadIdx.x;

    __shared__ u16 Wt[32][72];
    __shared__ u16 Sm[32][72];

    int wv   = tid >> 6, lane = tid & 63;
    int quad = lane >> 4, l16 = lane & 15;
    int px_half = wv & 1, ct = wv >> 1;

    int w_kq  = tid & 7;
    int w_cor = tid >> 3;

    int s_cp = tid & 31;
    int s_p0 = tid >> 5;

    const float* xb = x + b * CIN * HH * WW;

    f32x4 acc = (f32x4)(0.f);

    for (int chunk = 0; chunk < 18; ++chunk) {
        int tap = chunk >> 1;
        int koff = chunk * 64;
        int cb = chunk & 1;
        int ky = tap / 3, kx = tap % 3;
        int y  = ho - 1 + ky;
        bool yok = (y >= 0) && (y < HH);

        __syncthreads();

        *(uint4*)(&Wt[w_cor][w_kq * 8]) =
            *(const uint4*)(wofs + w_cor * CK + koff + w_kq * 8);

        const float* xr0 = xb + ((cb * 64 + 2 * s_cp) * HH + (yok ? y : 0)) * WW;
        const float* xr1 = xr0 + HH * WW;
#pragma unroll
        for (int j = 0; j < 4; ++j) {
            int px  = s_p0 + 8 * j;
            int col = wo0 + px + kx - 1;
            bool ok = yok && ((unsigned)col < WW);
            float v0 = ok ? xr0[col] : 0.f;
            float v1 = ok ? xr1[col] : 0.f;
            *(u32*)(&Sm[px][2 * s_cp]) = (u32)f2bf(v0) | ((u32)f2bf(v1) << 16);
        }
        __syncthreads();

#pragma unroll
        for (int ks = 0; ks < 2; ++ks) {
            s16x8 bfrag = *(const s16x8*)(&Sm[px_half * 16 + l16][ks * 32 + quad * 8]);
            s16x8 afrag = *(const s16x8*)(&Wt[ct * 16 + l16][ks * 32 + quad * 8]);
            acc = __builtin_amdgcn_mfma_f32_16x16x32_bf16(afrag, bfrag, acc, 0, 0, 0);
        }
    }

    int pxo = wo0 + px_half * 16 + l16;
#pragma unroll
    for (int r = 0; r < 4; ++r) {
        int co = ct * 16 + quad * 4 + r;
        if (co >= 27) break;
        float v = acc[r];
        if (co < 18) {
            v += ob[co];
            v = fminf(fmaxf(v, -16.f), 16.f);
        } else {
            v += mb[co - 18];
            v = 2.f / (1.f + expf(-v));
        }
        om[((b * 27 + co) * HH + ho) * WW + pxo] = v;
    }
}

// -------------------------------------------------------------------------
// Kernel 2: deformable sampling + bf16 MFMA GEMM.
// Round-7: afrag loads from fragment-ordered wfrag -> coalesced 1KB/wave
// loads (was 16 scattered 64B lines each). All 8 frags prefetched per
// chunk into regs. Pipeline/dbuf structure unchanged from round 6.
// -------------------------------------------------------------------------
__global__ __launch_bounds__(256, 4)
void dcn_mfma(const float* __restrict__ x, const float* __restrict__ om,
              const u16* __restrict__ wfrag, float* __restrict__ out) {
    int blkid = blockIdx.x;          // 1024 = BB*HH*4
    int xcd = blkid & 7, idx = blkid >> 3;
    int b   = xcd >> 1;
    int ho  = ((xcd & 1) << 5) + (idx >> 2);
    int wo0 = (idx & 3) << 4;
    int tid = threadIdx.x;

    __shared__ u16   Sm[2][16][72];    // 4.5 KB double-buffered
    __shared__ int   s_idx[16][KK][4]; // 2.25 KB
    __shared__ float s_wgt[16][KK][4]; // 2.25 KB

    if (tid < 16 * KK) {
        int p = tid / KK, k = tid - (tid / KK) * KK;
        int wo = wo0 + p;
        const float* omb = om + (b * 27) * HH * WW + ho * WW + wo;
        float offy = omb[(2 * k)     * HH * WW];
        float offx = omb[(2 * k + 1) * HH * WW];
        float mval = omb[(18 + k)    * HH * WW];

        float py = (float)(ho - 1 + k / 3) + offy;
        float px = (float)(wo - 1 + k % 3) + offx;
        float y0f = floorf(py), x0f = floorf(px);
        float wy1 = py - y0f,  wx1 = px - x0f;
        float wy0 = 1.f - wy1, wx0 = 1.f - wx1;
        int iy0 = (int)y0f, ix0 = (int)x0f;
        int iy1 = iy0 + 1,  ix1 = ix0 + 1;
        bool vy0 = (iy0 >= 0) && (iy0 < HH);
        bool vy1 = (iy1 >= 0) && (iy1 < HH);
        bool vx0 = (ix0 >= 0) && (ix0 < WW);
        bool vx1 = (ix1 >= 0) && (ix1 < WW);
        int cy0 = min(max(iy0, 0), HH - 1), cy1 = min(max(iy1, 0), HH - 1);
        int cx0 = min(max(ix0, 0), WW - 1), cx1 = min(max(ix1, 0), WW - 1);
        s_idx[p][k][0] = cy0 * WW + cx0;
        s_idx[p][k][1] = cy0 * WW + cx1;
        s_idx[p][k][2] = cy1 * WW + cx0;
        s_idx[p][k][3] = cy1 * WW + cx1;
        s_wgt[p][k][0] = (vy0 && vx0) ? mval * wy0 * wx0 : 0.f;
        s_wgt[p][k][1] = (vy0 && vx1) ? mval * wy0 * wx1 : 0.f;
        s_wgt[p][k][2] = (vy1 && vx0) ? mval * wy1 * wx0 : 0.f;
        s_wgt[p][k][3] = (vy1 && vx1) ? mval * wy1 * wx1 : 0.f;
    }
    __syncthreads();

    const float* xb = x + b * CIN * HH * WW;

    int wv   = tid >> 6, lane = tid & 63;
    int quad = lane >> 4, l16 = lane & 15;

    int s_px = tid & 15;     // sampling: lane sweeps px
    int s_cg = tid >> 4;     // c-pair group 0..15

    // fragment-ordered W: per (chunk) a wave reads 8 contiguous-1KB frags
    // at wq + chunk*16384 + ct*1024 + ks*512 (u16 units)
    const u16* wq = wfrag + wv * 4096 + lane * 8;

    f32x4 acc[4];
#pragma unroll
    for (int i = 0; i < 4; ++i) acc[i] = (f32x4)(0.f);

    auto gather = [&](int chunk, float v[4]) {
        int tap = chunk >> 1, cb = chunk & 1;
        int   i0 = s_idx[s_px][tap][0], i1 = s_idx[s_px][tap][1];
        int   i2 = s_idx[s_px][tap][2], i3 = s_idx[s_px][tap][3];
        float g0 = s_wgt[s_px][tap][0], g1 = s_wgt[s_px][tap][1];
        float g2 = s_wgt[s_px][tap][2], g3 = s_wgt[s_px][tap][3];
        const float* xcb = xb + cb * 64 * HH * WW;
#pragma unroll
        for (int j = 0; j < 2; ++j) {
            int c = 2 * s_cg + 32 * j;
            const float* xc0 = xcb + c * HH * WW;
            const float* xc1 = xc0 + HH * WW;
            v[2*j]   = g0 * xc0[i0] + g1 * xc0[i1] + g2 * xc0[i2] + g3 * xc0[i3];
            v[2*j+1] = g0 * xc1[i0] + g1 * xc1[i1] + g2 * xc1[i2] + g3 * xc1[i3];
        }
    };

    float vc[4], vn[4];
    gather(0, vc);
    int buf = 0;

    for (int chunk = 0; chunk < 18; ++chunk) {
        *(u32*)(&Sm[buf][s_px][2 * s_cg])      = (u32)f2bf(vc[0]) | ((u32)f2bf(vc[1]) << 16);
        *(u32*)(&Sm[buf][s_px][2 * s_cg + 32]) = (u32)f2bf(vc[2]) | ((u32)f2bf(vc[3]) << 16);
        __syncthreads();   // one barrier/iter; dbuf makes write(k+2)/read(k) safe

        // prefetch all 8 W fragments for this chunk (coalesced 1KB loads)
        const u16* wc = wq + chunk * 16384;
        s16x8 af[8];
#pragma unroll
        for (int ct = 0; ct < 4; ++ct) {
#pragma unroll
            for (int ks = 0; ks < 2; ++ks)
                af[ct * 2 + ks] = *(const s16x8*)(wc + ct * 1024 + ks * 512);
        }

        if (chunk < 17) gather(chunk + 1, vn);   // latency overlaps MFMAs

#pragma unroll
        for (int ks = 0; ks < 2; ++ks) {
            s16x8 bfrag = *(const s16x8*)(&Sm[buf][l16][ks * 32 + quad * 8]);
#pragma unroll
            for (int ct = 0; ct < 4; ++ct)
                acc[ct] = __builtin_amdgcn_mfma_f32_16x16x32_bf16(af[ct * 2 + ks], bfrag, acc[ct], 0, 0, 0);
        }
#pragma unroll
        for (int q = 0; q < 4; ++q) vc[q] = vn[q];
        buf ^= 1;
    }

#pragma unroll
    for (int ct = 0; ct < 4; ++ct) {
        int cobase = wv * 64 + ct * 16 + quad * 4;
#pragma unroll
        for (int r = 0; r < 4; ++r) {
            int co = cobase + r;
            out[((b * COUT + co) * HH + ho) * WW + wo0 + l16] = acc[ct][r];
        }
    }
}

// -------------------------------------------------------------------------
extern "C" void kernel_launch(void* const* d_in, const int* in_sizes, int n_in,
                              void* d_out, int out_size, void* d_ws, size_t ws_size,
                              hipStream_t stream) {
    const float* x  = (const float*)d_in[0];
    const float* ow = (const float*)d_in[1];
    const float* ob = (const float*)d_in[2];
    const float* mw = (const float*)d_in[3];
    const float* mb = (const float*)d_in[4];
    const float* wt = (const float*)d_in[5];

    char* ws = (char*)d_ws;
    u16*   wbf  = (u16*)ws;                          ws += (size_t)COUT * CK * 2;  // 576 KB
    u16*   wofs = (u16*)ws;                          ws += (size_t)32 * CK * 2;    // 72 KB
    float* om   = (float*)ws;                                                      // 1.77 MB
    float* out  = (float*)d_out;

    int n0 = COUT * CK;
    wprep<<<(n0 + 255) / 256, 256, 0, stream>>>(wt, wbf);

    int n0b = 32 * CK;
    wofs_prep<<<(n0b + 255) / 256, 256, 0, stream>>>(ow, mw, wofs);

    offmask_mfma<<<BB * HH * 2, 256, 0, stream>>>(x, wofs, ob, mb, om);

    dcn_mfma<<<BB * HH * 4, 256, 0, stream>>>(x, om, wbf, out);
}

// Round 8
// 133.118 us; speedup vs baseline: 9.5954x; 1.3893x over previous
//
#include <hip/hip_runtime.h>
#include <math.h>

#define CIN   128
#define COUT  256
#define HH    64
#define WW    64
#define BB    4
#define KK    9
#define CK    (CIN*KK)   // 1152

typedef unsigned short u16;
typedef unsigned int   u32;
using f32x4  = __attribute__((ext_vector_type(4))) float;
using s16x8  = __attribute__((ext_vector_type(8))) short;

__device__ __forceinline__ u16 f2bf(float f) {
    union { float f; u32 u; } v; v.f = f;
    u32 u = v.u;
    u += 0x7FFFu + ((u >> 16) & 1u);   // round-to-nearest-even
    return (u16)(u >> 16);
}
__device__ __forceinline__ float bf2f(u16 h) {
    union { u32 u; float f; } v; v.u = ((u32)h) << 16;
    return v.f;
}

// -------------------------------------------------------------------------
// Kernel 0x: x NCHW f32 -> NHWC bf16: xt[(b*4096 + y*64+xx)*128 + c]
// Block = (b, y); LDS tile transpose keeps both sides coalesced.
// -------------------------------------------------------------------------
__global__ __launch_bounds__(256)
void xprep(const float* __restrict__ x, u16* __restrict__ xt) {
    __shared__ u16 T[64][130];
    int b = blockIdx.x >> 6, y = blockIdx.x & 63;
    int tid = threadIdx.x;
    int lane = tid & 63, cw = tid >> 6;
    for (int c = cw; c < 128; c += 4)
        T[lane][c] = f2bf(x[((b * 128 + c) * 64 + y) * 64 + lane]);
    __syncthreads();
    int c = tid & 127;
    for (int p = tid >> 7; p < 64; p += 2)
        xt[((b * 64 + y) * 64 + p) * 128 + c] = T[p][c];
}

// -------------------------------------------------------------------------
// Kernel 0a: main weight -> MFMA-fragment-ordered bf16 (unchanged r7).
// wfrag idx = (((chunk*4+wv)*4+ct)*2+ks)*512 + lane*8 + j
// -------------------------------------------------------------------------
__global__ __launch_bounds__(256)
void wprep(const float* __restrict__ w, u16* __restrict__ wfrag) {
    int i = blockIdx.x * 256 + threadIdx.x;
    if (i >= COUT * CK) return;
    int j     = i & 7;
    int lane  = (i >> 3) & 63;
    int ks    = (i >> 9) & 1;
    int ct    = (i >> 10) & 3;
    int wv    = (i >> 12) & 3;
    int chunk = i >> 14;
    int co  = wv * 64 + ct * 16 + (lane & 15);
    int k   = chunk * 64 + ks * 32 + (lane >> 4) * 8 + j;
    int tap = k >> 7, c = k & 127;
    wfrag[i] = f2bf(w[co * CK + c * 9 + tap]);
}

// -------------------------------------------------------------------------
// Kernel 0b: offset+mask weights -> fragment-ordered (M=32: 2 tiles).
// wofsf idx = ((chunk*2 + t)*2 + ks)*512 + lane*8 + j
// co = t*16+(lane&15), k = chunk*64+ks*32+(lane>>4)*8+j (tap-major)
// -------------------------------------------------------------------------
__global__ __launch_bounds__(256)
void wofs_prep(const float* __restrict__ ow, const float* __restrict__ mw,
               u16* __restrict__ wofsf) {
    int i = blockIdx.x * 256 + threadIdx.x;
    if (i >= 32 * CK) return;
    int j     = i & 7;
    int lane  = (i >> 3) & 63;
    int ks    = (i >> 9) & 1;
    int t     = (i >> 10) & 1;
    int chunk = i >> 11;
    int co  = t * 16 + (lane & 15);
    int k   = chunk * 64 + ks * 32 + (lane >> 4) * 8 + j;
    int tap = k >> 7, c = k & 127;
    float v = 0.f;
    if (co < 18)      v = ow[co * CK + c * 9 + tap];
    else if (co < 27) v = mw[(co - 18) * CK + c * 9 + tap];
    wofsf[i] = f2bf(v);
}

// -------------------------------------------------------------------------
// Fused kernel: phase A = offset/mask GEMM (M=32, redundant across waves),
// bilinear params in LDS, phase B = deformable sampling + main MFMA GEMM
// (round-7 pipeline) with NHWC bf16 gathers (lane = channel).
// -------------------------------------------------------------------------
__global__ __launch_bounds__(256, 4)
void dcn_fused(const u16* __restrict__ xt, const u16* __restrict__ wofsf,
               const float* __restrict__ ob, const float* __restrict__ mb,
               const u16* __restrict__ wfrag, float* __restrict__ out) {
    int blkid = blockIdx.x;          // 1024 = BB*HH*4
    int xcd = blkid & 7, idx = blkid >> 3;
    int b   = xcd >> 1;
    int ho  = ((xcd & 1) << 5) + (idx >> 2);
    int wo0 = (idx & 3) << 4;
    int tid = threadIdx.x;

    __shared__ u16   Sm[2][16][72];     // 4.5 KB (A uses Sm[0]; B double-buffers)
    __shared__ float s_om[27][16];      // 1.7 KB offsets+masks for this px block
    __shared__ int   s_idx[16][KK][4];  // premultiplied by 128 (xt pos stride)
    __shared__ float s_wgt[16][KK][4];

    int wv   = tid >> 6, lane = tid & 63;
    int quad = lane >> 4, l16 = lane & 15;

    const u16* xtb = xt + (size_t)b * 4096 * 128;

    // ================= phase A: offset/mask GEMM =================
    f32x4 aco[2];
    aco[0] = (f32x4)(0.f); aco[1] = (f32x4)(0.f);

    for (int chunk = 0; chunk < 18; ++chunk) {
        int tap = chunk >> 1, cb = chunk & 1;
        int ky = tap / 3, kx = tap % 3;
        int y  = ho - 1 + ky;
        bool yok = (y >= 0) && (y < HH);

        __syncthreads();   // protect Sm[0] from previous chunk's readers
        // stage: 4 px per wave, lane = channel (coalesced 128B ushort loads)
#pragma unroll
        for (int pp = 0; pp < 4; ++pp) {
            int p   = wv * 4 + pp;
            int col = wo0 + p + kx - 1;
            bool ok = yok && ((unsigned)col < WW);
            u16 v = ok ? xtb[(size_t)(y * 64 + col) * 128 + cb * 64 + lane] : (u16)0;
            Sm[0][p][lane] = v;
        }
        __syncthreads();

        const u16* wc = wofsf + chunk * 2048 + lane * 8;
#pragma unroll
        for (int ks = 0; ks < 2; ++ks) {
            s16x8 bfrag = *(const s16x8*)(&Sm[0][l16][ks * 32 + quad * 8]);
#pragma unroll
            for (int t = 0; t < 2; ++t) {
                s16x8 afrag = *(const s16x8*)(wc + (t * 2 + ks) * 512);
                aco[t] = __builtin_amdgcn_mfma_f32_16x16x32_bf16(afrag, bfrag, aco[t], 0, 0, 0);
            }
        }
    }
    // epilogue A: wave 0 writes s_om (all waves computed identical bits)
    if (wv == 0) {
#pragma unroll
        for (int t = 0; t < 2; ++t) {
#pragma unroll
            for (int r = 0; r < 4; ++r) {
                int co = t * 16 + quad * 4 + r;
                if (co < 27) {
                    float v = aco[t][r];
                    if (co < 18) {
                        v += ob[co];
                        v = fminf(fmaxf(v, -16.f), 16.f);
                    } else {
                        v += mb[co - 18];
                        v = 2.f / (1.f + expf(-v));
                    }
                    s_om[co][l16] = v;
                }
            }
        }
    }
    __syncthreads();

    // bilinear corner params for 16 px x 9 taps
    if (tid < 16 * KK) {
        int p = tid / KK, k = tid - (tid / KK) * KK;
        int wo = wo0 + p;
        float offy = s_om[2 * k][p];
        float offx = s_om[2 * k + 1][p];
        float mval = s_om[18 + k][p];

        float py = (float)(ho - 1 + k / 3) + offy;
        float px = (float)(wo - 1 + k % 3) + offx;
        float y0f = floorf(py), x0f = floorf(px);
        float wy1 = py - y0f,  wx1 = px - x0f;
        float wy0 = 1.f - wy1, wx0 = 1.f - wx1;
        int iy0 = (int)y0f, ix0 = (int)x0f;
        int iy1 = iy0 + 1,  ix1 = ix0 + 1;
        bool vy0 = (iy0 >= 0) && (iy0 < HH);
        bool vy1 = (iy1 >= 0) && (iy1 < HH);
        bool vx0 = (ix0 >= 0) && (ix0 < WW);
        bool vx1 = (ix1 >= 0) && (ix1 < WW);
        int cy0 = min(max(iy0, 0), HH - 1), cy1 = min(max(iy1, 0), HH - 1);
        int cx0 = min(max(ix0, 0), WW - 1), cx1 = min(max(ix1, 0), WW - 1);
        s_idx[p][k][0] = (cy0 * WW + cx0) * 128;
        s_idx[p][k][1] = (cy0 * WW + cx1) * 128;
        s_idx[p][k][2] = (cy1 * WW + cx0) * 128;
        s_idx[p][k][3] = (cy1 * WW + cx1) * 128;
        s_wgt[p][k][0] = (vy0 && vx0) ? mval * wy0 * wx0 : 0.f;
        s_wgt[p][k][1] = (vy0 && vx1) ? mval * wy0 * wx1 : 0.f;
        s_wgt[p][k][2] = (vy1 && vx0) ? mval * wy1 * wx0 : 0.f;
        s_wgt[p][k][3] = (vy1 && vx1) ? mval * wy1 * wx1 : 0.f;
    }
    __syncthreads();

    // ================= phase B: sampling + main GEMM =================
    const u16* wq = wfrag + wv * 4096 + lane * 8;

    f32x4 acc[4];
#pragma unroll
    for (int i = 0; i < 4; ++i) acc[i] = (f32x4)(0.f);

    // gather: lane = channel; 4 px per wave; corners via LDS-broadcast idx
    auto gather = [&](int chunk, float v[4]) {
        int tap = chunk >> 1, cb = chunk & 1;
        int coff = cb * 64 + lane;
#pragma unroll
        for (int pp = 0; pp < 4; ++pp) {
            int p = wv * 4 + pp;
            int   i0 = s_idx[p][tap][0], i1 = s_idx[p][tap][1];
            int   i2 = s_idx[p][tap][2], i3 = s_idx[p][tap][3];
            float g0 = s_wgt[p][tap][0], g1 = s_wgt[p][tap][1];
            float g2 = s_wgt[p][tap][2], g3 = s_wgt[p][tap][3];
            float c0 = bf2f(xtb[i0 + coff]);
            float c1 = bf2f(xtb[i1 + coff]);
            float c2 = bf2f(xtb[i2 + coff]);
            float c3 = bf2f(xtb[i3 + coff]);
            v[pp] = g0 * c0 + g1 * c1 + g2 * c2 + g3 * c3;
        }
    };

    float vc[4], vn[4];
    gather(0, vc);
    int buf = 0;

    for (int chunk = 0; chunk < 18; ++chunk) {
#pragma unroll
        for (int pp = 0; pp < 4; ++pp)
            Sm[buf][wv * 4 + pp][lane] = f2bf(vc[pp]);
        __syncthreads();   // one barrier/iter; dbuf makes write(k+2)/read(k) safe

        // prefetch all 8 W fragments (coalesced 1KB loads)
        const u16* wc = wq + chunk * 16384;
        s16x8 af[8];
#pragma unroll
        for (int ct = 0; ct < 4; ++ct) {
#pragma unroll
            for (int ks = 0; ks < 2; ++ks)
                af[ct * 2 + ks] = *(const s16x8*)(wc + ct * 1024 + ks * 512);
        }

        if (chunk < 17) gather(chunk + 1, vn);   // latency overlaps MFMAs

#pragma unroll
        for (int ks = 0; ks < 2; ++ks) {
            s16x8 bfrag = *(const s16x8*)(&Sm[buf][l16][ks * 32 + quad * 8]);
#pragma unroll
            for (int ct = 0; ct < 4; ++ct)
                acc[ct] = __builtin_amdgcn_mfma_f32_16x16x32_bf16(af[ct * 2 + ks], bfrag, acc[ct], 0, 0, 0);
        }
#pragma unroll
        for (int q = 0; q < 4; ++q) vc[q] = vn[q];
        buf ^= 1;
    }

    // epilogue: col = l16 -> wo0+l16; row = quad*4+r -> co
#pragma unroll
    for (int ct = 0; ct < 4; ++ct) {
        int cobase = wv * 64 + ct * 16 + quad * 4;
#pragma unroll
        for (int r = 0; r < 4; ++r) {
            int co = cobase + r;
            out[((b * COUT + co) * HH + ho) * WW + wo0 + l16] = acc[ct][r];
        }
    }
}

// -------------------------------------------------------------------------
extern "C" void kernel_launch(void* const* d_in, const int* in_sizes, int n_in,
                              void* d_out, int out_size, void* d_ws, size_t ws_size,
                              hipStream_t stream) {
    const float* x  = (const float*)d_in[0];
    const float* ow = (const float*)d_in[1];
    const float* ob = (const float*)d_in[2];
    const float* mw = (const float*)d_in[3];
    const float* mb = (const float*)d_in[4];
    const float* wt = (const float*)d_in[5];

    char* ws = (char*)d_ws;
    u16* wfrag = (u16*)ws;  ws += (size_t)COUT * CK * 2;            // 576 KB
    u16* wofsf = (u16*)ws;  ws += (size_t)32 * CK * 2;              // 72 KB
    u16* xt    = (u16*)ws;                                          // 4 MB
    float* out = (float*)d_out;

    xprep<<<BB * 64, 256, 0, stream>>>(x, xt);

    int n0 = COUT * CK;
    wprep<<<(n0 + 255) / 256, 256, 0, stream>>>(wt, wfrag);

    int n0b = 32 * CK;
    wofs_prep<<<(n0b + 255) / 256, 256, 0, stream>>>(ow, mw, wofsf);

    dcn_fused<<<BB * HH * 4, 256, 0, stream>>>(xt, wofsf, ob, mb, wfrag, out);
}

// Round 9
// 111.804 us; speedup vs baseline: 11.4247x; 1.1906x over previous
//
#include <hip/hip_runtime.h>
#include <math.h>

#define CIN   128
#define COUT  256
#define HH    64
#define WW    64
#define BB    4
#define KK    9
#define CK    (CIN*KK)   // 1152

typedef unsigned short u16;
typedef unsigned int   u32;
using f32x4  = __attribute__((ext_vector_type(4))) float;
using s16x8  = __attribute__((ext_vector_type(8))) short;

__device__ __forceinline__ u16 f2bf(float f) {
    union { float f; u32 u; } v; v.f = f;
    u32 u = v.u;
    u += 0x7FFFu + ((u >> 16) & 1u);   // round-to-nearest-even
    return (u16)(u >> 16);
}
__device__ __forceinline__ float bflo(u32 u) {   // low u16 as bf16 -> f32
    union { u32 u; float f; } v; v.u = u << 16;
    return v.f;
}
__device__ __forceinline__ float bfhi(u32 u) {   // high u16 as bf16 -> f32
    union { u32 u; float f; } v; v.u = u & 0xFFFF0000u;
    return v.f;
}

// -------------------------------------------------------------------------
// prep_all: one launch for all preprocessing.
//  blocks [0,256):        x NCHW f32 -> NHWC bf16 xt[(b*4096+y*64+x)*128+c]
//  blocks [256,1408):     main W -> MFMA-fragment-ordered bf16
//                         wfrag idx = (((chunk*4+q)*4+ct)*2+ks)*512+lane*8+j
//  blocks [1408,1552):    offset/mask W -> fragment-ordered (M=32: 2 tiles)
//                         wofsf idx = ((chunk*2+t)*2+ks)*512+lane*8+j
// -------------------------------------------------------------------------
__global__ __launch_bounds__(256)
void prep_all(const float* __restrict__ x, const float* __restrict__ w,
              const float* __restrict__ ow, const float* __restrict__ mw,
              u16* __restrict__ xt, u16* __restrict__ wfrag,
              u16* __restrict__ wofsf) {
    __shared__ u16 T[64][130];
    int blk = blockIdx.x;
    int tid = threadIdx.x;

    if (blk < 256) {                         // ---- xprep ----
        int b = blk >> 6, y = blk & 63;
        int lane = tid & 63, cw = tid >> 6;
        for (int c = cw; c < 128; c += 4)
            T[lane][c] = f2bf(x[((b * 128 + c) * 64 + y) * 64 + lane]);
        __syncthreads();
        int c = tid & 127;
        for (int p = tid >> 7; p < 64; p += 2)
            xt[((b * 64 + y) * 64 + p) * 128 + c] = T[p][c];
    } else if (blk < 256 + 1152) {           // ---- wprep ----
        int i = (blk - 256) * 256 + tid;
        int j     = i & 7;
        int lane  = (i >> 3) & 63;
        int ks    = (i >> 9) & 1;
        int ct    = (i >> 10) & 3;
        int q     = (i >> 12) & 3;
        int chunk = i >> 14;
        int co  = q * 64 + ct * 16 + (lane & 15);
        int k   = chunk * 64 + ks * 32 + (lane >> 4) * 8 + j;
        int tap = k >> 7, c = k & 127;
        wfrag[i] = f2bf(w[co * CK + c * 9 + tap]);
    } else {                                 // ---- wofs_prep ----
        int i = (blk - 1408) * 256 + tid;
        if (i < 32 * CK) {
            int j     = i & 7;
            int lane  = (i >> 3) & 63;
            int ks    = (i >> 9) & 1;
            int t     = (i >> 10) & 1;
            int chunk = i >> 11;
            int co  = t * 16 + (lane & 15);
            int k   = chunk * 64 + ks * 32 + (lane >> 4) * 8 + j;
            int tap = k >> 7, c = k & 127;
            float v = 0.f;
            if (co < 18)      v = ow[co * CK + c * 9 + tap];
            else if (co < 27) v = mw[(co - 18) * CK + c * 9 + tap];
            wofsf[i] = f2bf(v);
        }
    }
}

// -------------------------------------------------------------------------
// Fused kernel, round-9: 512 threads, 32 px per block (grid 512 = 2/CU,
// 16 waves/CU). Each wave owns 2 co-tiles UNIQUELY and does both px
// halves -> W is read once per block (halves L2 W traffic vs r8).
// u32 two-channel gathers; both phases pipelined, 1 barrier/iter.
// -------------------------------------------------------------------------
__global__ __launch_bounds__(512, 4)
void dcn_fused(const u16* __restrict__ xt, const u16* __restrict__ wofsf,
               const float* __restrict__ ob, const float* __restrict__ mb,
               const u16* __restrict__ wfrag, float* __restrict__ out) {
    int blkid = blockIdx.x;          // 512 = BB*HH*2
    int xcd = blkid & 7, idx = blkid >> 3;     // idx 0..63
    int b   = xcd >> 1;
    int ho  = ((xcd & 1) << 5) + (idx >> 1);
    int wo0 = (idx & 1) << 5;
    int tid = threadIdx.x;

    __shared__ u16   Sm[2][32][72];     // 9 KB double-buffered, px rows
    __shared__ float s_om[27][32];      // offsets+masks for 32 px
    __shared__ int   s_idx[32][KK][4];  // corner pos * 128 (xt units)
    __shared__ float s_wgt[32][KK][4];

    int wv   = tid >> 6, lane = tid & 63;
    int quad = lane >> 4, l16 = lane & 15;

    int cp    = tid & 31;     // channel pair: channels 2cp, 2cp+1 of cb-half
    int pslot = tid >> 5;     // 0..15 -> px {2*pslot, 2*pslot+1}

    const u16* xtb = xt + (size_t)b * 4096 * 128;

    // ================= phase A: offset/mask GEMM (M=32) =================
    int pa_ph = wv & 1;                 // px half this wave computes
    f32x4 aco[2];
    aco[0] = (f32x4)(0.f); aco[1] = (f32x4)(0.f);

    u32 ra[2];
    auto pa_gather = [&](int chunk) {
        int tap = chunk >> 1, cb = chunk & 1;
        int kx = tap % 3;
        int y  = ho - 1 + tap / 3;
        bool yok = (y >= 0) && (y < HH);
#pragma unroll
        for (int s = 0; s < 2; ++s) {
            int px  = 2 * pslot + s;
            int col = wo0 + px + kx - 1;
            bool ok = yok && ((unsigned)col < WW);
            ra[s] = ok ? *(const u32*)(xtb + (size_t)(y * 64 + col) * 128 + cb * 64 + 2 * cp)
                       : 0u;
        }
    };

    pa_gather(0);
    int buf = 0;
    for (int chunk = 0; chunk < 18; ++chunk) {
        *(u32*)(&Sm[buf][2 * pslot][2 * cp])     = ra[0];
        *(u32*)(&Sm[buf][2 * pslot + 1][2 * cp]) = ra[1];
        __syncthreads();
        if (chunk < 17) pa_gather(chunk + 1);    // latency overlaps MFMAs

        const u16* wc = wofsf + chunk * 2048 + lane * 8;
#pragma unroll
        for (int ks = 0; ks < 2; ++ks) {
            s16x8 bfrag = *(const s16x8*)(&Sm[buf][pa_ph * 16 + l16][ks * 32 + quad * 8]);
#pragma unroll
            for (int t = 0; t < 2; ++t) {
                s16x8 afrag = *(const s16x8*)(wc + (t * 2 + ks) * 512);
                aco[t] = __builtin_amdgcn_mfma_f32_16x16x32_bf16(afrag, bfrag, aco[t], 0, 0, 0);
            }
        }
        buf ^= 1;
    }
    // epilogue A: wave 0 writes px half 0, wave 1 writes px half 1
    if (wv < 2) {
#pragma unroll
        for (int t = 0; t < 2; ++t) {
#pragma unroll
            for (int r = 0; r < 4; ++r) {
                int co = t * 16 + quad * 4 + r;
                if (co < 27) {
                    float v = aco[t][r];
                    if (co < 18) {
                        v += ob[co];
                        v = fminf(fmaxf(v, -16.f), 16.f);   // max_offset = 16
                    } else {
                        v += mb[co - 18];
                        v = 2.f / (1.f + expf(-v));         // 2*sigmoid
                    }
                    s_om[co][pa_ph * 16 + l16] = v;
                }
            }
        }
    }
    __syncthreads();

    // bilinear corner params for 32 px x 9 taps
    if (tid < 32 * KK) {
        int p = tid / KK, k = tid - (tid / KK) * KK;
        int wo = wo0 + p;
        float offy = s_om[2 * k][p];
        float offx = s_om[2 * k + 1][p];
        float mval = s_om[18 + k][p];

        float py = (float)(ho - 1 + k / 3) + offy;
        float px = (float)(wo - 1 + k % 3) + offx;
        float y0f = floorf(py), x0f = floorf(px);
        float wy1 = py - y0f,  wx1 = px - x0f;
        float wy0 = 1.f - wy1, wx0 = 1.f - wx1;
        int iy0 = (int)y0f, ix0 = (int)x0f;
        int iy1 = iy0 + 1,  ix1 = ix0 + 1;
        bool vy0 = (iy0 >= 0) && (iy0 < HH);
        bool vy1 = (iy1 >= 0) && (iy1 < HH);
        bool vx0 = (ix0 >= 0) && (ix0 < WW);
        bool vx1 = (ix1 >= 0) && (ix1 < WW);
        int cy0 = min(max(iy0, 0), HH - 1), cy1 = min(max(iy1, 0), HH - 1);
        int cx0 = min(max(ix0, 0), WW - 1), cx1 = min(max(ix1, 0), WW - 1);
        s_idx[p][k][0] = (cy0 * WW + cx0) * 128;
        s_idx[p][k][1] = (cy0 * WW + cx1) * 128;
        s_idx[p][k][2] = (cy1 * WW + cx0) * 128;
        s_idx[p][k][3] = (cy1 * WW + cx1) * 128;
        s_wgt[p][k][0] = (vy0 && vx0) ? mval * wy0 * wx0 : 0.f;
        s_wgt[p][k][1] = (vy0 && vx1) ? mval * wy0 * wx1 : 0.f;
        s_wgt[p][k][2] = (vy1 && vx0) ? mval * wy1 * wx0 : 0.f;
        s_wgt[p][k][3] = (vy1 && vx1) ? mval * wy1 * wx1 : 0.f;
    }
    __syncthreads();

    // ================= phase B: sampling + main GEMM =================
    const u16* wq = wfrag + lane * 8;

    f32x4 acc[2][2];                 // [co-tile t][px half ph]
#pragma unroll
    for (int t = 0; t < 2; ++t) { acc[t][0] = (f32x4)(0.f); acc[t][1] = (f32x4)(0.f); }

    float vlo[2], vhi[2];
    auto gather = [&](int chunk) {
        int tap = chunk >> 1, cb = chunk & 1;
        int coff = cb * 64 + 2 * cp;
#pragma unroll
        for (int s = 0; s < 2; ++s) {
            int p = 2 * pslot + s;
            int   i0 = s_idx[p][tap][0], i1 = s_idx[p][tap][1];
            int   i2 = s_idx[p][tap][2], i3 = s_idx[p][tap][3];
            float g0 = s_wgt[p][tap][0], g1 = s_wgt[p][tap][1];
            float g2 = s_wgt[p][tap][2], g3 = s_wgt[p][tap][3];
            u32 u0 = *(const u32*)(xtb + i0 + coff);
            u32 u1 = *(const u32*)(xtb + i1 + coff);
            u32 u2 = *(const u32*)(xtb + i2 + coff);
            u32 u3 = *(const u32*)(xtb + i3 + coff);
            vlo[s] = g0 * bflo(u0) + g1 * bflo(u1) + g2 * bflo(u2) + g3 * bflo(u3);
            vhi[s] = g0 * bfhi(u0) + g1 * bfhi(u1) + g2 * bfhi(u2) + g3 * bfhi(u3);
        }
    };

    gather(0);
    buf = 0;
    for (int chunk = 0; chunk < 18; ++chunk) {
        *(u32*)(&Sm[buf][2 * pslot][2 * cp]) =
            (u32)f2bf(vlo[0]) | ((u32)f2bf(vhi[0]) << 16);
        *(u32*)(&Sm[buf][2 * pslot + 1][2 * cp]) =
            (u32)f2bf(vlo[1]) | ((u32)f2bf(vhi[1]) << 16);
        __syncthreads();   // one barrier/iter; dbuf makes write(k+2)/read(k) safe

        // prefetch this chunk's 4 unique W fragments (2 tiles x 2 ks)
        const u16* wc = wq + chunk * 16384;
        s16x8 af[4];
#pragma unroll
        for (int t = 0; t < 2; ++t)
#pragma unroll
            for (int ks = 0; ks < 2; ++ks)
                af[t * 2 + ks] = *(const s16x8*)(wc + ((wv * 2 + t) * 2 + ks) * 512);

        if (chunk < 17) gather(chunk + 1);   // latency overlaps MFMAs

#pragma unroll
        for (int ks = 0; ks < 2; ++ks) {
            s16x8 bf0 = *(const s16x8*)(&Sm[buf][l16][ks * 32 + quad * 8]);
            s16x8 bf1 = *(const s16x8*)(&Sm[buf][16 + l16][ks * 32 + quad * 8]);
#pragma unroll
            for (int t = 0; t < 2; ++t) {
                acc[t][0] = __builtin_amdgcn_mfma_f32_16x16x32_bf16(af[t * 2 + ks], bf0, acc[t][0], 0, 0, 0);
                acc[t][1] = __builtin_amdgcn_mfma_f32_16x16x32_bf16(af[t * 2 + ks], bf1, acc[t][1], 0, 0, 0);
            }
        }
        buf ^= 1;
    }

    // epilogue: co = (wv*2+t)*16 + quad*4 + r; px = wo0 + ph*16 + l16
#pragma unroll
    for (int t = 0; t < 2; ++t) {
        int cobase = (wv * 2 + t) * 16 + quad * 4;
#pragma unroll
        for (int ph = 0; ph < 2; ++ph) {
#pragma unroll
            for (int r = 0; r < 4; ++r) {
                int co = cobase + r;
                out[((b * COUT + co) * HH + ho) * WW + wo0 + ph * 16 + l16] = acc[t][ph][r];
            }
        }
    }
}

// -------------------------------------------------------------------------
extern "C" void kernel_launch(void* const* d_in, const int* in_sizes, int n_in,
                              void* d_out, int out_size, void* d_ws, size_t ws_size,
                              hipStream_t stream) {
    const float* x  = (const float*)d_in[0];
    const float* ow = (const float*)d_in[1];
    const float* ob = (const float*)d_in[2];
    const float* mw = (const float*)d_in[3];
    const float* mb = (const float*)d_in[4];
    const float* wt = (const float*)d_in[5];

    char* ws = (char*)d_ws;
    u16* wfrag = (u16*)ws;  ws += (size_t)COUT * CK * 2;            // 576 KB
    u16* wofsf = (u16*)ws;  ws += (size_t)32 * CK * 2;              // 72 KB
    u16* xt    = (u16*)ws;                                          // 4 MB
    float* out = (float*)d_out;

    prep_all<<<1552, 256, 0, stream>>>(x, wt, ow, mw, xt, wfrag, wofsf);

    dcn_fused<<<BB * HH * 2, 512, 0, stream>>>(xt, wofsf, ob, mb, wfrag, out);
}

// Round 10
// 103.755 us; speedup vs baseline: 12.3109x; 1.0776x over previous
//
#include <hip/hip_runtime.h>
#include <math.h>

#define CIN   128
#define COUT  256
#define HH    64
#define WW    64
#define BB    4
#define KK    9
#define CK    (CIN*KK)   // 1152

typedef unsigned short u16;
typedef unsigned int   u32;
using f32x4  = __attribute__((ext_vector_type(4))) float;
using s16x8  = __attribute__((ext_vector_type(8))) short;

__device__ __forceinline__ u16 f2bf(float f) {
    union { float f; u32 u; } v; v.f = f;
    u32 u = v.u;
    u += 0x7FFFu + ((u >> 16) & 1u);   // round-to-nearest-even
    return (u16)(u >> 16);
}
__device__ __forceinline__ float bfel(s16x8 v, int j) {
    union { u32 u; float f; } c; c.u = ((u32)(u16)v[j]) << 16; return c.f;
}
__device__ __forceinline__ u32 pk2(float a, float b) {
    return (u32)f2bf(a) | ((u32)f2bf(b) << 16);
}

// -------------------------------------------------------------------------
// prep_all (unchanged from round 9): xt NHWC bf16, wfrag / wofsf
// fragment-ordered bf16.
// -------------------------------------------------------------------------
__global__ __launch_bounds__(256)
void prep_all(const float* __restrict__ x, const float* __restrict__ w,
              const float* __restrict__ ow, const float* __restrict__ mw,
              u16* __restrict__ xt, u16* __restrict__ wfrag,
              u16* __restrict__ wofsf) {
    __shared__ u16 T[64][130];
    int blk = blockIdx.x;
    int tid = threadIdx.x;

    if (blk < 256) {                         // ---- xprep ----
        int b = blk >> 6, y = blk & 63;
        int lane = tid & 63, cw = tid >> 6;
        for (int c = cw; c < 128; c += 4)
            T[lane][c] = f2bf(x[((b * 128 + c) * 64 + y) * 64 + lane]);
        __syncthreads();
        int c = tid & 127;
        for (int p = tid >> 7; p < 64; p += 2)
            xt[((b * 64 + y) * 64 + p) * 128 + c] = T[p][c];
    } else if (blk < 256 + 1152) {           // ---- wprep ----
        int i = (blk - 256) * 256 + tid;
        int j     = i & 7;
        int lane  = (i >> 3) & 63;
        int ks    = (i >> 9) & 1;
        int ct    = (i >> 10) & 3;
        int q     = (i >> 12) & 3;
        int chunk = i >> 14;
        int co  = q * 64 + ct * 16 + (lane & 15);
        int k   = chunk * 64 + ks * 32 + (lane >> 4) * 8 + j;
        int tap = k >> 7, c = k & 127;
        wfrag[i] = f2bf(w[co * CK + c * 9 + tap]);
    } else {                                 // ---- wofs_prep ----
        int i = (blk - 1408) * 256 + tid;
        if (i < 32 * CK) {
            int j     = i & 7;
            int lane  = (i >> 3) & 63;
            int ks    = (i >> 9) & 1;
            int t     = (i >> 10) & 1;
            int chunk = i >> 11;
            int co  = t * 16 + (lane & 15);
            int k   = chunk * 64 + ks * 32 + (lane >> 4) * 8 + j;
            int tap = k >> 7, c = k & 127;
            float v = 0.f;
            if (co < 18)      v = ow[co * CK + c * 9 + tap];
            else if (co < 27) v = mw[(co - 18) * CK + c * 9 + tap];
            wofsf[i] = f2bf(v);
        }
    }
}

// -------------------------------------------------------------------------
// Fused kernel, round-10: tap-granularity staging (128 ch per iter),
// 16B/lane dwordx4 accesses. Lane roles: px = wv*4+(lane>>4), oct=lane&15.
// Sampling: 4 corner loads/wave/tap (was 16). Same accumulation order as
// r9 -> bitwise-identical output. 512 thr, 32 px, grid 512.
// -------------------------------------------------------------------------
__global__ __launch_bounds__(512, 4)
void dcn_fused(const u16* __restrict__ xt, const u16* __restrict__ wofsf,
               const float* __restrict__ ob, const float* __restrict__ mb,
               const u16* __restrict__ wfrag, float* __restrict__ out) {
    int blkid = blockIdx.x;          // 512 = BB*HH*2
    int xcd = blkid & 7, idx = blkid >> 3;
    int b   = xcd >> 1;
    int ho  = ((xcd & 1) << 5) + (idx >> 1);
    int wo0 = (idx & 1) << 5;
    int tid = threadIdx.x;

    __shared__ __align__(16) u16 Sm[2][32][136];  // 17 KB dbuf, stride 136 u16
    __shared__ float s_om[27][32];
    __shared__ int   s_idx[32][KK][4];  // corner pos * 128 (xt units)
    __shared__ float s_wgt[32][KK][4];

    int wv   = tid >> 6, lane = tid & 63;
    int quad = lane >> 4, l16 = lane & 15;
    int gpx  = wv * 4 + (lane >> 4);    // px this lane stages (0..31)
    int oct  = lane & 15;               // channel-oct (8 ch)

    const u16* xtb = xt + (size_t)b * 4096 * 128;
    const s16x8 vzero = {0,0,0,0,0,0,0,0};

    // ================= phase A: offset/mask GEMM (M=32) =================
    int pa_ph = wv & 1;
    f32x4 aco[2];
    aco[0] = (f32x4)(0.f); aco[1] = (f32x4)(0.f);

    s16x8 sa;
    auto pa_gather = [&](int tap) {
        int kx = tap % 3;
        int y  = ho - 1 + tap / 3;
        bool yok = (unsigned)y < HH;
        int col = wo0 + gpx + kx - 1;
        bool ok = yok && ((unsigned)col < WW);
        int yc = yok ? y : 0;
        int cc = ((unsigned)col < WW) ? col : 0;
        sa = *(const s16x8*)(xtb + (size_t)(yc * 64 + cc) * 128 + oct * 8);
        if (!ok) sa = vzero;
    };

    pa_gather(0);
    int buf = 0;
    for (int tap = 0; tap < 9; ++tap) {
        *(s16x8*)(&Sm[buf][gpx][oct * 8]) = sa;
        __syncthreads();
        if (tap < 8) pa_gather(tap + 1);

        if (wv < 2) {    // waves >=2 were redundant in phase A
            const u16* wc = wofsf + lane * 8;
#pragma unroll
            for (int ks4 = 0; ks4 < 4; ++ks4) {
                int chunkA = tap * 2 + (ks4 >> 1);
                s16x8 bfrag = *(const s16x8*)(&Sm[buf][pa_ph * 16 + l16][ks4 * 32 + quad * 8]);
#pragma unroll
                for (int t = 0; t < 2; ++t) {
                    s16x8 afrag = *(const s16x8*)(wc + ((chunkA * 2 + t) * 2 + (ks4 & 1)) * 512);
                    aco[t] = __builtin_amdgcn_mfma_f32_16x16x32_bf16(afrag, bfrag, aco[t], 0, 0, 0);
                }
            }
        }
        buf ^= 1;
    }
    // epilogue A: wave 0 -> px half 0, wave 1 -> px half 1
    if (wv < 2) {
#pragma unroll
        for (int t = 0; t < 2; ++t) {
#pragma unroll
            for (int r = 0; r < 4; ++r) {
                int co = t * 16 + quad * 4 + r;
                if (co < 27) {
                    float v = aco[t][r];
                    if (co < 18) {
                        v += ob[co];
                        v = fminf(fmaxf(v, -16.f), 16.f);   // max_offset = 16
                    } else {
                        v += mb[co - 18];
                        v = 2.f / (1.f + expf(-v));         // 2*sigmoid
                    }
                    s_om[co][pa_ph * 16 + l16] = v;
                }
            }
        }
    }
    __syncthreads();

    // bilinear corner params for 32 px x 9 taps
    if (tid < 32 * KK) {
        int p = tid / KK, k = tid - (tid / KK) * KK;
        int wo = wo0 + p;
        float offy = s_om[2 * k][p];
        float offx = s_om[2 * k + 1][p];
        float mval = s_om[18 + k][p];

        float py = (float)(ho - 1 + k / 3) + offy;
        float px = (float)(wo - 1 + k % 3) + offx;
        float y0f = floorf(py), x0f = floorf(px);
        float wy1 = py - y0f,  wx1 = px - x0f;
        float wy0 = 1.f - wy1, wx0 = 1.f - wx1;
        int iy0 = (int)y0f, ix0 = (int)x0f;
        int iy1 = iy0 + 1,  ix1 = ix0 + 1;
        bool vy0 = (iy0 >= 0) && (iy0 < HH);
        bool vy1 = (iy1 >= 0) && (iy1 < HH);
        bool vx0 = (ix0 >= 0) && (ix0 < WW);
        bool vx1 = (ix1 >= 0) && (ix1 < WW);
        int cy0 = min(max(iy0, 0), HH - 1), cy1 = min(max(iy1, 0), HH - 1);
        int cx0 = min(max(ix0, 0), WW - 1), cx1 = min(max(ix1, 0), WW - 1);
        s_idx[p][k][0] = (cy0 * WW + cx0) * 128;
        s_idx[p][k][1] = (cy0 * WW + cx1) * 128;
        s_idx[p][k][2] = (cy1 * WW + cx0) * 128;
        s_idx[p][k][3] = (cy1 * WW + cx1) * 128;
        s_wgt[p][k][0] = (vy0 && vx0) ? mval * wy0 * wx0 : 0.f;
        s_wgt[p][k][1] = (vy0 && vx1) ? mval * wy0 * wx1 : 0.f;
        s_wgt[p][k][2] = (vy1 && vx0) ? mval * wy1 * wx0 : 0.f;
        s_wgt[p][k][3] = (vy1 && vx1) ? mval * wy1 * wx1 : 0.f;
    }
    __syncthreads();

    // ================= phase B: sampling + main GEMM =================
    const u16* wq = wfrag + lane * 8;

    f32x4 acc[2][2];                 // [co-tile t][px half ph]
#pragma unroll
    for (int t = 0; t < 2; ++t) { acc[t][0] = (f32x4)(0.f); acc[t][1] = (f32x4)(0.f); }

    s16x8 cr0, cr1, cr2, cr3;
    float gg0, gg1, gg2, gg3;
    auto gatherB = [&](int tap) {
        int i0 = s_idx[gpx][tap][0], i1 = s_idx[gpx][tap][1];
        int i2 = s_idx[gpx][tap][2], i3 = s_idx[gpx][tap][3];
        gg0 = s_wgt[gpx][tap][0]; gg1 = s_wgt[gpx][tap][1];
        gg2 = s_wgt[gpx][tap][2]; gg3 = s_wgt[gpx][tap][3];
        int co8 = oct * 8;
        cr0 = *(const s16x8*)(xtb + i0 + co8);
        cr1 = *(const s16x8*)(xtb + i1 + co8);
        cr2 = *(const s16x8*)(xtb + i2 + co8);
        cr3 = *(const s16x8*)(xtb + i3 + co8);
    };

    gatherB(0);
    buf = 0;
    for (int tap = 0; tap < 9; ++tap) {
        // blend 4 corners -> 8 bf16 channels, store 16B
        float o[8];
#pragma unroll
        for (int j = 0; j < 8; ++j)
            o[j] = gg0 * bfel(cr0, j) + gg1 * bfel(cr1, j)
                 + gg2 * bfel(cr2, j) + gg3 * bfel(cr3, j);
        uint4 pkv;
        pkv.x = pk2(o[0], o[1]); pkv.y = pk2(o[2], o[3]);
        pkv.z = pk2(o[4], o[5]); pkv.w = pk2(o[6], o[7]);
        *(uint4*)(&Sm[buf][gpx][oct * 8]) = pkv;
        __syncthreads();   // one barrier/iter; dbuf makes write(t+2)/read(t) safe

        // prefetch this tap's 8 unique W fragments (2 tiles x 4 ks)
        s16x8 af[8];
#pragma unroll
        for (int t = 0; t < 2; ++t)
#pragma unroll
            for (int ks4 = 0; ks4 < 4; ++ks4) {
                int chunkB = tap * 2 + (ks4 >> 1);
                af[t * 4 + ks4] = *(const s16x8*)(
                    wq + ((chunkB * 16 + (wv * 2 + t)) * 2 + (ks4 & 1)) * 512);
            }

        if (tap < 8) gatherB(tap + 1);   // corner-load latency overlaps MFMAs

#pragma unroll
        for (int ks4 = 0; ks4 < 4; ++ks4) {
            s16x8 bf0 = *(const s16x8*)(&Sm[buf][l16][ks4 * 32 + quad * 8]);
            s16x8 bf1 = *(const s16x8*)(&Sm[buf][16 + l16][ks4 * 32 + quad * 8]);
#pragma unroll
            for (int t = 0; t < 2; ++t) {
                acc[t][0] = __builtin_amdgcn_mfma_f32_16x16x32_bf16(af[t * 4 + ks4], bf0, acc[t][0], 0, 0, 0);
                acc[t][1] = __builtin_amdgcn_mfma_f32_16x16x32_bf16(af[t * 4 + ks4], bf1, acc[t][1], 0, 0, 0);
            }
        }
        buf ^= 1;
    }

    // epilogue: co = (wv*2+t)*16 + quad*4 + r; px = wo0 + ph*16 + l16
#pragma unroll
    for (int t = 0; t < 2; ++t) {
        int cobase = (wv * 2 + t) * 16 + quad * 4;
#pragma unroll
        for (int ph = 0; ph < 2; ++ph) {
#pragma unroll
            for (int r = 0; r < 4; ++r) {
                int co = cobase + r;
                out[((b * COUT + co) * HH + ho) * WW + wo0 + ph * 16 + l16] = acc[t][ph][r];
            }
        }
    }
}

// -------------------------------------------------------------------------
extern "C" void kernel_launch(void* const* d_in, const int* in_sizes, int n_in,
                              void* d_out, int out_size, void* d_ws, size_t ws_size,
                              hipStream_t stream) {
    const float* x  = (const float*)d_in[0];
    const float* ow = (const float*)d_in[1];
    const float* ob = (const float*)d_in[2];
    const float* mw = (const float*)d_in[3];
    const float* mb = (const float*)d_in[4];
    const float* wt = (const float*)d_in[5];

    char* ws = (char*)d_ws;
    u16* wfrag = (u16*)ws;  ws += (size_t)COUT * CK * 2;            // 576 KB
    u16* wofsf = (u16*)ws;  ws += (size_t)32 * CK * 2;              // 72 KB
    u16* xt    = (u16*)ws;                                          // 4 MB
    float* out = (float*)d_out;

    prep_all<<<1552, 256, 0, stream>>>(x, wt, ow, mw, xt, wfrag, wofsf);

    dcn_fused<<<BB * HH * 2, 512, 0, stream>>>(xt, wofsf, ob, mb, wfrag, out);
}

// Round 11
// 103.615 us; speedup vs baseline: 12.3276x; 1.0014x over previous
//
#include <hip/hip_runtime.h>
#include <math.h>

#define CIN   128
#define COUT  256
#define HH    64
#define WW    64
#define BB    4
#define KK    9
#define CK    (CIN*KK)   // 1152

typedef unsigned short u16;
typedef unsigned int   u32;
using f32x4  = __attribute__((ext_vector_type(4))) float;
using s16x8  = __attribute__((ext_vector_type(8))) short;

__device__ __forceinline__ u16 f2bf(float f) {
    union { float f; u32 u; } v; v.f = f;
    u32 u = v.u;
    u += 0x7FFFu + ((u >> 16) & 1u);   // round-to-nearest-even
    return (u16)(u >> 16);
}
__device__ __forceinline__ float bfel(s16x8 v, int j) {
    union { u32 u; float f; } c; c.u = ((u32)(u16)v[j]) << 16; return c.f;
}
__device__ __forceinline__ u32 asu(float f) {
    union { float f; u32 u; } v; v.f = f; return v.u;
}

// -------------------------------------------------------------------------
// prep_all: xt NHWC bf16; W layouts are per-(tap[,wave]) contiguous so the
// fused kernel's per-tap fragment loads are base+small-offset:
//  wfrag idx = ((((tap*8+wv)*2+t)*4+ks4)*512) + lane*8 + j   (8KB/tap/wave)
//  wofsf idx = (((tap*2+t)*4+ks4)*512) + lane*8 + j          (8KB/tap)
//  with co = (wv*2+t)*16+(lane&15) [wv=0 for wofsf], k = tap*128+ks4*32+
//  (lane>>4)*8+j (tap-major k: tap=k>>7, c=k&127).
// -------------------------------------------------------------------------
__global__ __launch_bounds__(256)
void prep_all(const float* __restrict__ x, const float* __restrict__ w,
              const float* __restrict__ ow, const float* __restrict__ mw,
              u16* __restrict__ xt, u16* __restrict__ wfrag,
              u16* __restrict__ wofsf) {
    __shared__ u16 T[64][130];
    int blk = blockIdx.x;
    int tid = threadIdx.x;

    if (blk < 256) {                         // ---- xprep ----
        int b = blk >> 6, y = blk & 63;
        int lane = tid & 63, cw = tid >> 6;
        for (int c = cw; c < 128; c += 4)
            T[lane][c] = f2bf(x[((b * 128 + c) * 64 + y) * 64 + lane]);
        __syncthreads();
        int c = tid & 127;
        for (int p = tid >> 7; p < 64; p += 2)
            xt[((b * 64 + y) * 64 + p) * 128 + c] = T[p][c];
    } else if (blk < 256 + 1152) {           // ---- wprep ----
        int i = (blk - 256) * 256 + tid;
        int j    = i & 7;
        int lane = (i >> 3) & 63;
        int ks4  = (i >> 9) & 3;
        int t    = (i >> 11) & 1;
        int wv   = (i >> 12) & 7;
        int tap  = i >> 15;                  // 0..8
        int co = (wv * 2 + t) * 16 + (lane & 15);
        int k  = tap * 128 + ks4 * 32 + (lane >> 4) * 8 + j;
        int c  = k & 127;
        wfrag[i] = f2bf(w[co * CK + c * 9 + tap]);
    } else {                                 // ---- wofs_prep ----
        int i = (blk - 1408) * 256 + tid;
        if (i < 9 * 4096) {
            int j    = i & 7;
            int lane = (i >> 3) & 63;
            int ks4  = (i >> 9) & 3;
            int t    = (i >> 11) & 1;
            int tap  = i >> 12;              // 0..8
            int co = t * 16 + (lane & 15);
            int k  = tap * 128 + ks4 * 32 + (lane >> 4) * 8 + j;
            int c  = k & 127;
            float v = 0.f;
            if (co < 18)      v = ow[co * CK + c * 9 + tap];
            else if (co < 27) v = mw[(co - 18) * CK + c * 9 + tap];
            wofsf[i] = f2bf(v);
        }
    }
}

// -------------------------------------------------------------------------
// Fused kernel, round-11: (a) per-(tap,wave) contiguous W fragment loads,
// (b) truncation-pack for phase-B LDS stores, (c) 2-deep gather pipeline
// in both phases (register rotation, unrolled tap loops).
// -------------------------------------------------------------------------
__global__ __launch_bounds__(512, 4)
void dcn_fused(const u16* __restrict__ xt, const u16* __restrict__ wofsf,
               const float* __restrict__ ob, const float* __restrict__ mb,
               const u16* __restrict__ wfrag, float* __restrict__ out) {
    int blkid = blockIdx.x;          // 512 = BB*HH*2
    int xcd = blkid & 7, idx = blkid >> 3;
    int b   = xcd >> 1;
    int ho  = ((xcd & 1) << 5) + (idx >> 1);
    int wo0 = (idx & 1) << 5;
    int tid = threadIdx.x;

    __shared__ __align__(16) u16 Sm[2][32][136];  // 17 KB dbuf, stride 136 u16
    __shared__ float s_om[27][32];
    __shared__ int   s_idx[32][KK][4];  // corner pos * 128 (xt units)
    __shared__ float s_wgt[32][KK][4];

    int wv   = tid >> 6, lane = tid & 63;
    int quad = lane >> 4, l16 = lane & 15;
    int gpx  = wv * 4 + (lane >> 4);    // px this lane stages (0..31)
    int oct  = lane & 15;               // channel-oct (8 ch)

    const u16* xtb = xt + (size_t)b * 4096 * 128;
    const s16x8 vzero = {0,0,0,0,0,0,0,0};

    // ================= phase A: offset/mask GEMM (M=32) =================
    int pa_ph = wv & 1;
    f32x4 aco[2];
    aco[0] = (f32x4)(0.f); aco[1] = (f32x4)(0.f);

    s16x8 sreg[2];
    auto pa_gather = [&](int tap, int slot) {
        int kx = tap % 3;
        int y  = ho - 1 + tap / 3;
        bool yok = (unsigned)y < HH;
        int col = wo0 + gpx + kx - 1;
        bool ok = yok && ((unsigned)col < WW);
        int yc = yok ? y : 0;
        int cc = ((unsigned)col < WW) ? col : 0;
        s16x8 v = *(const s16x8*)(xtb + (size_t)(yc * 64 + cc) * 128 + oct * 8);
        sreg[slot] = ok ? v : vzero;
    };

    pa_gather(0, 0);
    pa_gather(1, 1);
    int buf = 0;
#pragma unroll
    for (int tap = 0; tap < 9; ++tap) {
        int sl = tap & 1;
        *(s16x8*)(&Sm[buf][gpx][oct * 8]) = sreg[sl];
        __syncthreads();
        if (tap + 2 < 9) pa_gather(tap + 2, sl);   // 2-deep lookahead

        if (wv < 2) {    // waves >=2 are redundant in phase A
            const u16* wc = wofsf + tap * 4096 + lane * 8;
#pragma unroll
            for (int ks4 = 0; ks4 < 4; ++ks4) {
                s16x8 bfrag = *(const s16x8*)(&Sm[buf][pa_ph * 16 + l16][ks4 * 32 + quad * 8]);
#pragma unroll
                for (int t = 0; t < 2; ++t) {
                    s16x8 afrag = *(const s16x8*)(wc + (t * 4 + ks4) * 512);
                    aco[t] = __builtin_amdgcn_mfma_f32_16x16x32_bf16(afrag, bfrag, aco[t], 0, 0, 0);
                }
            }
        }
        buf ^= 1;
    }
    // epilogue A: wave 0 -> px half 0, wave 1 -> px half 1
    if (wv < 2) {
#pragma unroll
        for (int t = 0; t < 2; ++t) {
#pragma unroll
            for (int r = 0; r < 4; ++r) {
                int co = t * 16 + quad * 4 + r;
                if (co < 27) {
                    float v = aco[t][r];
                    if (co < 18) {
                        v += ob[co];
                        v = fminf(fmaxf(v, -16.f), 16.f);   // max_offset = 16
                    } else {
                        v += mb[co - 18];
                        v = 2.f / (1.f + expf(-v));         // 2*sigmoid
                    }
                    s_om[co][pa_ph * 16 + l16] = v;
                }
            }
        }
    }
    __syncthreads();

    // bilinear corner params for 32 px x 9 taps
    if (tid < 32 * KK) {
        int p = tid / KK, k = tid - (tid / KK) * KK;
        int wo = wo0 + p;
        float offy = s_om[2 * k][p];
        float offx = s_om[2 * k + 1][p];
        float mval = s_om[18 + k][p];

        float py = (float)(ho - 1 + k / 3) + offy;
        float px = (float)(wo - 1 + k % 3) + offx;
        float y0f = floorf(py), x0f = floorf(px);
        float wy1 = py - y0f,  wx1 = px - x0f;
        float wy0 = 1.f - wy1, wx0 = 1.f - wx1;
        int iy0 = (int)y0f, ix0 = (int)x0f;
        int iy1 = iy0 + 1,  ix1 = ix0 + 1;
        bool vy0 = (iy0 >= 0) && (iy0 < HH);
        bool vy1 = (iy1 >= 0) && (iy1 < HH);
        bool vx0 = (ix0 >= 0) && (ix0 < WW);
        bool vx1 = (ix1 >= 0) && (ix1 < WW);
        int cy0 = min(max(iy0, 0), HH - 1), cy1 = min(max(iy1, 0), HH - 1);
        int cx0 = min(max(ix0, 0), WW - 1), cx1 = min(max(ix1, 0), WW - 1);
        s_idx[p][k][0] = (cy0 * WW + cx0) * 128;
        s_idx[p][k][1] = (cy0 * WW + cx1) * 128;
        s_idx[p][k][2] = (cy1 * WW + cx0) * 128;
        s_idx[p][k][3] = (cy1 * WW + cx1) * 128;
        s_wgt[p][k][0] = (vy0 && vx0) ? mval * wy0 * wx0 : 0.f;
        s_wgt[p][k][1] = (vy0 && vx1) ? mval * wy0 * wx1 : 0.f;
        s_wgt[p][k][2] = (vy1 && vx0) ? mval * wy1 * wx0 : 0.f;
        s_wgt[p][k][3] = (vy1 && vx1) ? mval * wy1 * wx1 : 0.f;
    }
    __syncthreads();

    // ================= phase B: sampling + main GEMM =================
    f32x4 acc[2][2];                 // [co-tile t][px half ph]
#pragma unroll
    for (int t = 0; t < 2; ++t) { acc[t][0] = (f32x4)(0.f); acc[t][1] = (f32x4)(0.f); }

    s16x8 crs[2][4];
    float gs[2][4];
    auto gatherB = [&](int tap, int slot) {
        int i0 = s_idx[gpx][tap][0], i1 = s_idx[gpx][tap][1];
        int i2 = s_idx[gpx][tap][2], i3 = s_idx[gpx][tap][3];
        gs[slot][0] = s_wgt[gpx][tap][0]; gs[slot][1] = s_wgt[gpx][tap][1];
        gs[slot][2] = s_wgt[gpx][tap][2]; gs[slot][3] = s_wgt[gpx][tap][3];
        int co8 = oct * 8;
        crs[slot][0] = *(const s16x8*)(xtb + i0 + co8);
        crs[slot][1] = *(const s16x8*)(xtb + i1 + co8);
        crs[slot][2] = *(const s16x8*)(xtb + i2 + co8);
        crs[slot][3] = *(const s16x8*)(xtb + i3 + co8);
    };

    gatherB(0, 0);
    gatherB(1, 1);
    buf = 0;
#pragma unroll
    for (int tap = 0; tap < 9; ++tap) {
        int sl = tap & 1;
        // blend 4 corners -> 8 channels; truncation-pack to bf16 pairs
        float g0 = gs[sl][0], g1 = gs[sl][1], g2 = gs[sl][2], g3 = gs[sl][3];
        float o[8];
#pragma unroll
        for (int j = 0; j < 8; ++j)
            o[j] = g0 * bfel(crs[sl][0], j) + g1 * bfel(crs[sl][1], j)
                 + g2 * bfel(crs[sl][2], j) + g3 * bfel(crs[sl][3], j);
        uint4 pkv;
        pkv.x = (asu(o[1]) & 0xFFFF0000u) | (asu(o[0]) >> 16);
        pkv.y = (asu(o[3]) & 0xFFFF0000u) | (asu(o[2]) >> 16);
        pkv.z = (asu(o[5]) & 0xFFFF0000u) | (asu(o[4]) >> 16);
        pkv.w = (asu(o[7]) & 0xFFFF0000u) | (asu(o[6]) >> 16);
        *(uint4*)(&Sm[buf][gpx][oct * 8]) = pkv;
        __syncthreads();   // one barrier/iter; dbuf makes write(t+2)/read(t) safe

        if (tap + 2 < 9) gatherB(tap + 2, sl);   // 2-deep lookahead

        // this tap's 8 unique W fragments: one contiguous 8KB run per wave
        const u16* wc = wfrag + (tap * 8 + wv) * 4096 + lane * 8;
        s16x8 af[8];
#pragma unroll
        for (int t = 0; t < 2; ++t)
#pragma unroll
            for (int ks4 = 0; ks4 < 4; ++ks4)
                af[t * 4 + ks4] = *(const s16x8*)(wc + (t * 4 + ks4) * 512);

#pragma unroll
        for (int ks4 = 0; ks4 < 4; ++ks4) {
            s16x8 bf0 = *(const s16x8*)(&Sm[buf][l16][ks4 * 32 + quad * 8]);
            s16x8 bf1 = *(const s16x8*)(&Sm[buf][16 + l16][ks4 * 32 + quad * 8]);
#pragma unroll
            for (int t = 0; t < 2; ++t) {
                acc[t][0] = __builtin_amdgcn_mfma_f32_16x16x32_bf16(af[t * 4 + ks4], bf0, acc[t][0], 0, 0, 0);
                acc[t][1] = __builtin_amdgcn_mfma_f32_16x16x32_bf16(af[t * 4 + ks4], bf1, acc[t][1], 0, 0, 0);
            }
        }
        buf ^= 1;
    }

    // epilogue: co = (wv*2+t)*16 + quad*4 + r; px = wo0 + ph*16 + l16
#pragma unroll
    for (int t = 0; t < 2; ++t) {
        int cobase = (wv * 2 + t) * 16 + quad * 4;
#pragma unroll
        for (int ph = 0; ph < 2; ++ph) {
#pragma unroll
            for (int r = 0; r < 4; ++r) {
                int co = cobase + r;
                out[((b * COUT + co) * HH + ho) * WW + wo0 + ph * 16 + l16] = acc[t][ph][r];
            }
        }
    }
}

// -------------------------------------------------------------------------
extern "C" void kernel_launch(void* const* d_in, const int* in_sizes, int n_in,
                              void* d_out, int out_size, void* d_ws, size_t ws_size,
                              hipStream_t stream) {
    const float* x  = (const float*)d_in[0];
    const float* ow = (const float*)d_in[1];
    const float* ob = (const float*)d_in[2];
    const float* mw = (const float*)d_in[3];
    const float* mb = (const float*)d_in[4];
    const float* wt = (const float*)d_in[5];

    char* ws = (char*)d_ws;
    u16* wfrag = (u16*)ws;  ws += (size_t)COUT * CK * 2;            // 576 KB
    u16* wofsf = (u16*)ws;  ws += (size_t)32 * CK * 2;              // 72 KB
    u16* xt    = (u16*)ws;                                          // 4 MB
    float* out = (float*)d_out;

    prep_all<<<1552, 256, 0, stream>>>(x, wt, ow, mw, xt, wfrag, wofsf);

    dcn_fused<<<BB * HH * 2, 512, 0, stream>>>(xt, wofsf, ob, mb, wfrag, out);
}

// Round 13
// 103.202 us; speedup vs baseline: 12.3769x; 1.0040x over previous
//
#include <hip/hip_runtime.h>
#include <math.h>

#define CIN   128
#define COUT  256
#define HH    64
#define WW    64
#define BB    4
#define KK    9
#define CK    (CIN*KK)   // 1152

typedef unsigned short u16;
typedef unsigned int   u32;
using f32x4  = __attribute__((ext_vector_type(4))) float;
using s16x8  = __attribute__((ext_vector_type(8))) short;

__device__ __forceinline__ u16 f2bf(float f) {
    union { float f; u32 u; } v; v.f = f;
    u32 u = v.u;
    u += 0x7FFFu + ((u >> 16) & 1u);   // round-to-nearest-even
    return (u16)(u >> 16);
}
__device__ __forceinline__ float bfel(s16x8 v, int j) {
    union { u32 u; float f; } c; c.u = ((u32)(u16)v[j]) << 16; return c.f;
}
__device__ __forceinline__ u32 asu(float f) {
    union { float f; u32 u; } v; v.f = f; return v.u;
}

// -------------------------------------------------------------------------
// prep_all (identical to round 11): xt NHWC bf16; W fragment-ordered:
//  wfrag idx = ((((tap*8+wv)*2+t)*4+ks4)*512) + lane*8 + j   (8KB/tap/wave)
//  wofsf idx = (((tap*2+t)*4+ks4)*512) + lane*8 + j          (8KB/tap)
// -------------------------------------------------------------------------
__global__ __launch_bounds__(256)
void prep_all(const float* __restrict__ x, const float* __restrict__ w,
              const float* __restrict__ ow, const float* __restrict__ mw,
              u16* __restrict__ xt, u16* __restrict__ wfrag,
              u16* __restrict__ wofsf) {
    __shared__ u16 T[64][130];
    int blk = blockIdx.x;
    int tid = threadIdx.x;

    if (blk < 256) {                         // ---- xprep ----
        int b = blk >> 6, y = blk & 63;
        int lane = tid & 63, cw = tid >> 6;
        for (int c = cw; c < 128; c += 4)
            T[lane][c] = f2bf(x[((b * 128 + c) * 64 + y) * 64 + lane]);
        __syncthreads();
        int c = tid & 127;
        for (int p = tid >> 7; p < 64; p += 2)
            xt[((b * 64 + y) * 64 + p) * 128 + c] = T[p][c];
    } else if (blk < 256 + 1152) {           // ---- wprep ----
        int i = (blk - 256) * 256 + tid;
        int j    = i & 7;
        int lane = (i >> 3) & 63;
        int ks4  = (i >> 9) & 3;
        int t    = (i >> 11) & 1;
        int wv   = (i >> 12) & 7;
        int tap  = i >> 15;                  // 0..8
        int co = (wv * 2 + t) * 16 + (lane & 15);
        int k  = tap * 128 + ks4 * 32 + (lane >> 4) * 8 + j;
        int c  = k & 127;
        wfrag[i] = f2bf(w[co * CK + c * 9 + tap]);
    } else {                                 // ---- wofs_prep ----
        int i = (blk - 1408) * 256 + tid;
        if (i < 9 * 4096) {
            int j    = i & 7;
            int lane = (i >> 3) & 63;
            int ks4  = (i >> 9) & 3;
            int t    = (i >> 11) & 1;
            int tap  = i >> 12;              // 0..8
            int co = t * 16 + (lane & 15);
            int k  = tap * 128 + ks4 * 32 + (lane >> 4) * 8 + j;
            int c  = k & 127;
            float v = 0.f;
            if (co < 18)      v = ow[co * CK + c * 9 + tap];
            else if (co < 27) v = mw[(co - 18) * CK + c * 9 + tap];
            wofsf[i] = f2bf(v);
        }
    }
}

// -------------------------------------------------------------------------
// Fused kernel, round-13: r11 body with TWO TAPS PER BARRIER in both
// phases (4-slot Sm, 34.8KB; barriers 18 -> 10). Accumulation order per
// tap/ks4 unchanged -> bitwise-identical output vs r11.
// -------------------------------------------------------------------------
__global__ __launch_bounds__(512, 4)
void dcn_fused(const u16* __restrict__ xt, const u16* __restrict__ wofsf,
               const float* __restrict__ ob, const float* __restrict__ mb,
               const u16* __restrict__ wfrag, float* __restrict__ out) {
    int blkid = blockIdx.x;          // 512 = BB*HH*2
    int xcd = blkid & 7, idx = blkid >> 3;
    int b   = xcd >> 1;
    int ho  = ((xcd & 1) << 5) + (idx >> 1);
    int wo0 = (idx & 1) << 5;
    int tid = threadIdx.x;

    __shared__ __align__(16) u16 Sm[4][32][136];  // 34.8 KB, 4 tap slots
    __shared__ float s_om[27][32];
    __shared__ int   s_idx[32][KK][4];  // corner pos * 128 (xt units)
    __shared__ float s_wgt[32][KK][4];

    int wv   = tid >> 6, lane = tid & 63;
    int quad = lane >> 4, l16 = lane & 15;
    int gpx  = wv * 4 + (lane >> 4);    // px this lane stages (0..31)
    int oct  = lane & 15;               // channel-oct (8 ch)

    const u16* xtb = xt + (size_t)b * 4096 * 128;
    const s16x8 vzero = {0,0,0,0,0,0,0,0};

    // ================= phase A: offset/mask GEMM (M=32) =================
    int pa_ph = wv & 1;
    f32x4 aco[2];
    aco[0] = (f32x4)(0.f); aco[1] = (f32x4)(0.f);

    s16x8 sA[2][2];                     // [slot-pair][tap-in-pair]
    auto pa_gather = [&](int tap, int sp, int ti) {
        int kx = tap % 3;
        int y  = ho - 1 + tap / 3;
        bool yok = (unsigned)y < HH;
        int col = wo0 + gpx + kx - 1;
        bool ok = yok && ((unsigned)col < WW);
        int yc = yok ? y : 0;
        int cc = ((unsigned)col < WW) ? col : 0;
        s16x8 v = *(const s16x8*)(xtb + (size_t)(yc * 64 + cc) * 128 + oct * 8);
        sA[sp][ti] = ok ? v : vzero;
    };

    auto pa_mfma_tap = [&](int tap, int slot) {
        const u16* wc = wofsf + tap * 4096 + lane * 8;
#pragma unroll
        for (int ks4 = 0; ks4 < 4; ++ks4) {
            s16x8 bfrag = *(const s16x8*)(&Sm[slot][pa_ph * 16 + l16][ks4 * 32 + quad * 8]);
#pragma unroll
            for (int t = 0; t < 2; ++t) {
                s16x8 afrag = *(const s16x8*)(wc + (t * 4 + ks4) * 512);
                aco[t] = __builtin_amdgcn_mfma_f32_16x16x32_bf16(afrag, bfrag, aco[t], 0, 0, 0);
            }
        }
    };

    pa_gather(0, 0, 0);
    pa_gather(1, 0, 1);
#pragma unroll
    for (int p = 0; p < 4; ++p) {       // tap pairs (0,1)(2,3)(4,5)(6,7)
        int sp = p & 1;
        *(s16x8*)(&Sm[2 * sp    ][gpx][oct * 8]) = sA[sp][0];
        *(s16x8*)(&Sm[2 * sp + 1][gpx][oct * 8]) = sA[sp][1];
        __syncthreads();
        if (p < 3) { pa_gather(2 * p + 2, sp ^ 1, 0); pa_gather(2 * p + 3, sp ^ 1, 1); }
        else       { pa_gather(8,         sp ^ 1, 0); }
        if (wv < 2) {                   // waves >=2 are redundant in phase A
            pa_mfma_tap(2 * p,     2 * sp);
            pa_mfma_tap(2 * p + 1, 2 * sp + 1);
        }
    }
    // tail: tap 8 (in sA[0][0]; Sm[0] last read at p=2, barrier p=3 since)
    *(s16x8*)(&Sm[0][gpx][oct * 8]) = sA[0][0];
    __syncthreads();
    if (wv < 2) pa_mfma_tap(8, 0);

    // epilogue A: wave 0 -> px half 0, wave 1 -> px half 1
    if (wv < 2) {
#pragma unroll
        for (int t = 0; t < 2; ++t) {
#pragma unroll
            for (int r = 0; r < 4; ++r) {
                int co = t * 16 + quad * 4 + r;
                if (co < 27) {
                    float v = aco[t][r];
                    if (co < 18) {
                        v += ob[co];
                        v = fminf(fmaxf(v, -16.f), 16.f);   // max_offset = 16
                    } else {
                        v += mb[co - 18];
                        v = 2.f / (1.f + expf(-v));         // 2*sigmoid
                    }
                    s_om[co][pa_ph * 16 + l16] = v;
                }
            }
        }
    }
    __syncthreads();

    // bilinear corner params for 32 px x 9 taps
    if (tid < 32 * KK) {
        int p = tid / KK, k = tid - (tid / KK) * KK;
        int wo = wo0 + p;
        float offy = s_om[2 * k][p];
        float offx = s_om[2 * k + 1][p];
        float mval = s_om[18 + k][p];

        float py = (float)(ho - 1 + k / 3) + offy;
        float px = (float)(wo - 1 + k % 3) + offx;
        float y0f = floorf(py), x0f = floorf(px);
        float wy1 = py - y0f,  wx1 = px - x0f;
        float wy0 = 1.f - wy1, wx0 = 1.f - wx1;
        int iy0 = (int)y0f, ix0 = (int)x0f;
        int iy1 = iy0 + 1,  ix1 = ix0 + 1;
        bool vy0 = (iy0 >= 0) && (iy0 < HH);
        bool vy1 = (iy1 >= 0) && (iy1 < HH);
        bool vx0 = (ix0 >= 0) && (ix0 < WW);
        bool vx1 = (ix1 >= 0) && (ix1 < WW);
        int cy0 = min(max(iy0, 0), HH - 1), cy1 = min(max(iy1, 0), HH - 1);
        int cx0 = min(max(ix0, 0), WW - 1), cx1 = min(max(ix1, 0), WW - 1);
        s_idx[p][k][0] = (cy0 * WW + cx0) * 128;
        s_idx[p][k][1] = (cy0 * WW + cx1) * 128;
        s_idx[p][k][2] = (cy1 * WW + cx0) * 128;
        s_idx[p][k][3] = (cy1 * WW + cx1) * 128;
        s_wgt[p][k][0] = (vy0 && vx0) ? mval * wy0 * wx0 : 0.f;
        s_wgt[p][k][1] = (vy0 && vx1) ? mval * wy0 * wx1 : 0.f;
        s_wgt[p][k][2] = (vy1 && vx0) ? mval * wy1 * wx0 : 0.f;
        s_wgt[p][k][3] = (vy1 && vx1) ? mval * wy1 * wx1 : 0.f;
    }
    __syncthreads();

    // ================= phase B: sampling + main GEMM =================
    f32x4 acc[2][2];                 // [co-tile t][px half ph]
#pragma unroll
    for (int t = 0; t < 2; ++t) { acc[t][0] = (f32x4)(0.f); acc[t][1] = (f32x4)(0.f); }

    s16x8 crs[2][2][4];              // [slot-pair][tap-in-pair][corner]
    float gs[2][2][4];
    auto gatherB = [&](int tap, int sp, int ti) {
        int i0 = s_idx[gpx][tap][0], i1 = s_idx[gpx][tap][1];
        int i2 = s_idx[gpx][tap][2], i3 = s_idx[gpx][tap][3];
        gs[sp][ti][0] = s_wgt[gpx][tap][0]; gs[sp][ti][1] = s_wgt[gpx][tap][1];
        gs[sp][ti][2] = s_wgt[gpx][tap][2]; gs[sp][ti][3] = s_wgt[gpx][tap][3];
        int co8 = oct * 8;
        crs[sp][ti][0] = *(const s16x8*)(xtb + i0 + co8);
        crs[sp][ti][1] = *(const s16x8*)(xtb + i1 + co8);
        crs[sp][ti][2] = *(const s16x8*)(xtb + i2 + co8);
        crs[sp][ti][3] = *(const s16x8*)(xtb + i3 + co8);
    };

    auto blend_store = [&](int sp, int ti, int slot) {
        float g0 = gs[sp][ti][0], g1 = gs[sp][ti][1];
        float g2 = gs[sp][ti][2], g3 = gs[sp][ti][3];
        float o[8];
#pragma unroll
        for (int j = 0; j < 8; ++j)
            o[j] = g0 * bfel(crs[sp][ti][0], j) + g1 * bfel(crs[sp][ti][1], j)
                 + g2 * bfel(crs[sp][ti][2], j) + g3 * bfel(crs[sp][ti][3], j);
        uint4 pkv;
        pkv.x = (asu(o[1]) & 0xFFFF0000u) | (asu(o[0]) >> 16);
        pkv.y = (asu(o[3]) & 0xFFFF0000u) | (asu(o[2]) >> 16);
        pkv.z = (asu(o[5]) & 0xFFFF0000u) | (asu(o[4]) >> 16);
        pkv.w = (asu(o[7]) & 0xFFFF0000u) | (asu(o[6]) >> 16);
        *(uint4*)(&Sm[slot][gpx][oct * 8]) = pkv;
    };

    auto pb_mfma_tap = [&](int tap, int slot) {
        const u16* wc = wfrag + (tap * 8 + wv) * 4096 + lane * 8;
        s16x8 af[8];
#pragma unroll
        for (int t = 0; t < 2; ++t)
#pragma unroll
            for (int ks4 = 0; ks4 < 4; ++ks4)
                af[t * 4 + ks4] = *(const s16x8*)(wc + (t * 4 + ks4) * 512);
#pragma unroll
        for (int ks4 = 0; ks4 < 4; ++ks4) {
            s16x8 bf0 = *(const s16x8*)(&Sm[slot][l16][ks4 * 32 + quad * 8]);
            s16x8 bf1 = *(const s16x8*)(&Sm[slot][16 + l16][ks4 * 32 + quad * 8]);
#pragma unroll
            for (int t = 0; t < 2; ++t) {
                acc[t][0] = __builtin_amdgcn_mfma_f32_16x16x32_bf16(af[t * 4 + ks4], bf0, acc[t][0], 0, 0, 0);
                acc[t][1] = __builtin_amdgcn_mfma_f32_16x16x32_bf16(af[t * 4 + ks4], bf1, acc[t][1], 0, 0, 0);
            }
        }
    };

    gatherB(0, 0, 0);
    gatherB(1, 0, 1);
#pragma unroll
    for (int p = 0; p < 4; ++p) {       // tap pairs (0,1)(2,3)(4,5)(6,7)
        int sp = p & 1;
        blend_store(sp, 0, 2 * sp);
        blend_store(sp, 1, 2 * sp + 1);
        __syncthreads();
        if (p < 3) { gatherB(2 * p + 2, sp ^ 1, 0); gatherB(2 * p + 3, sp ^ 1, 1); }
        else       { gatherB(8,         sp ^ 1, 0); }
        pb_mfma_tap(2 * p,     2 * sp);
        pb_mfma_tap(2 * p + 1, 2 * sp + 1);
    }
    // tail: tap 8
    blend_store(0, 0, 0);
    __syncthreads();
    pb_mfma_tap(8, 0);

    // epilogue: co = (wv*2+t)*16 + quad*4 + r; px = wo0 + ph*16 + l16
#pragma unroll
    for (int t = 0; t < 2; ++t) {
        int cobase = (wv * 2 + t) * 16 + quad * 4;
#pragma unroll
        for (int ph = 0; ph < 2; ++ph) {
#pragma unroll
            for (int r = 0; r < 4; ++r) {
                int co = cobase + r;
                out[((b * COUT + co) * HH + ho) * WW + wo0 + ph * 16 + l16] = acc[t][ph][r];
            }
        }
    }
}

// -------------------------------------------------------------------------
extern "C" void kernel_launch(void* const* d_in, const int* in_sizes, int n_in,
                              void* d_out, int out_size, void* d_ws, size_t ws_size,
                              hipStream_t stream) {
    const float* x  = (const float*)d_in[0];
    const float* ow = (const float*)d_in[1];
    const float* ob = (const float*)d_in[2];
    const float* mw = (const float*)d_in[3];
    const float* mb = (const float*)d_in[4];
    const float* wt = (const float*)d_in[5];

    char* ws = (char*)d_ws;
    u16* wfrag = (u16*)ws;  ws += (size_t)COUT * CK * 2;            // 576 KB
    u16* wofsf = (u16*)ws;  ws += (size_t)32 * CK * 2;              // 72 KB
    u16* xt    = (u16*)ws;                                          // 4 MB
    float* out = (float*)d_out;

    prep_all<<<1552, 256, 0, stream>>>(x, wt, ow, mw, xt, wfrag, wofsf);

    dcn_fused<<<BB * HH * 2, 512, 0, stream>>>(xt, wofsf, ob, mb, wfrag, out);
}